// Round 1
// baseline (1488.287 us; speedup 1.0000x reference)
//
#include <hip/hip_runtime.h>
#include <math.h>

#define B 8
#define T 4
#define HID 2048
#define H 32
#define HKV 8
#define D 64
#define S 8192
#define ST (S + T)            // 8196
#define NREP (H / HKV)        // 4
#define EPS 1e-6f
#define SCALE 0.125f          // D^-0.5

#define GM 32                 // GEMM rows (B*T)
#define KC 512                // GEMM split-K chunk
#define SC 256                // attention S-chunk
#define NC ((ST + SC - 1) / SC)   // 33

// ---------------- split-K GEMM: y[m,col] += sum_i x[m,i]*W[i,col] ----------------
// 256 threads, each owns one col; acc over 32 rows in registers.
__global__ __launch_bounds__(256) void gemm_splitk(const float* __restrict__ x, int ldx,
                                                   const float* __restrict__ w, int N,
                                                   float* __restrict__ y) {
    __shared__ float xs[GM][64];
    const int col = blockIdx.x * 256 + threadIdx.x;
    const int i0base = blockIdx.y * KC;
    float acc[GM];
#pragma unroll
    for (int m = 0; m < GM; ++m) acc[m] = 0.f;
    for (int ic = 0; ic < KC; ic += 64) {
        const int i0 = i0base + ic;
        for (int j = threadIdx.x; j < GM * 64; j += 256) {
            const int m = j >> 6, ii = j & 63;
            xs[m][ii] = x[(size_t)m * ldx + i0 + ii];
        }
        __syncthreads();
#pragma unroll 8
        for (int ii = 0; ii < 64; ++ii) {
            const float wv = w[(size_t)(i0 + ii) * N + col];
#pragma unroll
            for (int m = 0; m < GM; ++m) acc[m] += xs[m][ii] * wv;
        }
        __syncthreads();
    }
#pragma unroll
    for (int m = 0; m < GM; ++m) atomicAdd(&y[(size_t)m * N + col], acc[m]);
}

// ---------------- rmsnorm + rope on q,k; scatter new k,v into k_full/v_full ------
__global__ __launch_bounds__(256) void qkv_post(const float* __restrict__ q_raw,   // [32][2048]
                                                const float* __restrict__ k_raw,   // [32][512]
                                                const float* __restrict__ v_raw,   // [32][512]
                                                const float* __restrict__ cosb,    // [32][64]
                                                const float* __restrict__ sinb,
                                                const float* __restrict__ qnw,
                                                const float* __restrict__ knw,
                                                float* __restrict__ q_fin,         // [32][H][64] (b,t,h,d)
                                                float* __restrict__ kfull,
                                                float* __restrict__ vfull) {
    const int wid = (blockIdx.x * 256 + threadIdx.x) >> 6;   // global wave id, 0..1535
    const int lane = threadIdx.x & 63;
    if (wid < 1024) {                       // q rows: m in 0..31, h in 0..31
        const int m = wid >> 5, h = wid & 31;
        float v = q_raw[(size_t)m * 2048 + h * 64 + lane];
        float ss = v * v;
#pragma unroll
        for (int off = 32; off; off >>= 1) ss += __shfl_xor(ss, off);
        float nv = qnw[lane] * v * rsqrtf(ss * (1.f / 64.f) + EPS);
        float other = __shfl_xor(nv, 32);
        float rot = (lane < 32) ? -other : other;
        float outv = nv * cosb[m * 64 + lane] + rot * sinb[m * 64 + lane];
        q_fin[(size_t)m * 2048 + h * 64 + lane] = outv * SCALE;
    } else if (wid < 1280) {                // k rows: m, g
        const int idx = wid - 1024;
        const int m = idx >> 3, g = idx & 7;
        float v = k_raw[(size_t)m * 512 + g * 64 + lane];
        float ss = v * v;
#pragma unroll
        for (int off = 32; off; off >>= 1) ss += __shfl_xor(ss, off);
        float nv = knw[lane] * v * rsqrtf(ss * (1.f / 64.f) + EPS);
        float other = __shfl_xor(nv, 32);
        float rot = (lane < 32) ? -other : other;
        float outv = nv * cosb[m * 64 + lane] + rot * sinb[m * 64 + lane];
        const int b = m >> 2, t = m & 3;
        kfull[((size_t)(b * HKV + g) * ST + S + t) * D + lane] = outv;
    } else if (wid < 1536) {                // v rows
        const int idx = wid - 1280;
        const int m = idx >> 3, g = idx & 7;
        float v = v_raw[(size_t)m * 512 + g * 64 + lane];
        const int b = m >> 2, t = m & 3;
        vfull[((size_t)(b * HKV + g) * ST + S + t) * D + lane] = v;
    }
}

// ---------------- fused: cache copy + attention partials (flash-decoding) -------
// block = (bg, chunk c). Streams K/V chunk from cache (c<32) or k_full tail (c=32),
// writes cache chunks into k_full/v_full, computes per-chunk m/l/o partials.
__global__ __launch_bounds__(256) void attn_part(const float* __restrict__ q_fin,
                                                 const float* __restrict__ ck,
                                                 const float* __restrict__ cv,
                                                 float* __restrict__ kfull,
                                                 float* __restrict__ vfull,
                                                 float* __restrict__ o_part,   // [64][16][NC][64]
                                                 float* __restrict__ ml_part)  // [64][16][NC][2]
{
    const int bg = blockIdx.x;            // 0..63
    const int c  = blockIdx.y;            // 0..NC-1
    const int b = bg >> 3, g = bg & 7;
    const int tid = threadIdx.x;

    __shared__ float qs[16][64];
    __shared__ float sc[16][SC];
    __shared__ float mrow[16], lrow[16];

    // load 16 q rows (row = r*4 + t)
    for (int j = tid; j < 16 * 64; j += 256) {
        const int row = j >> 6, d = j & 63;
        const int r = row >> 2, t = row & 3;
        qs[row][d] = q_fin[((size_t)(b * T + t) * H + (g * NREP + r)) * D + d];
    }
    __syncthreads();

    const int valid = min(SC, ST - c * SC);
    const bool from_cache = (c < S / SC);

    const float* kbase = from_cache ? (ck + ((size_t)bg * S + (size_t)c * SC) * D)
                                    : (kfull + ((size_t)bg * ST + (size_t)c * SC) * D);
    float* kdst = kfull + ((size_t)bg * ST + (size_t)c * SC) * D;

    // ---- scores: 4 threads per s (16 d each), 64 s per pass ----
    const int s_sub = tid >> 2;        // 0..63
    const int dpart = tid & 3;         // 0..3
    for (int sg = 0; sg < SC; sg += 64) {
        const int s = sg + s_sub;
        float kfrag[16];
        if (s < valid) {
            const float4* kr = (const float4*)(kbase + (size_t)s * D + dpart * 16);
            float4* kw4 = (float4*)(kdst + (size_t)s * D + dpart * 16);
#pragma unroll
            for (int q4 = 0; q4 < 4; ++q4) {
                const float4 kv = kr[q4];
                if (from_cache) kw4[q4] = kv;
                kfrag[q4 * 4 + 0] = kv.x; kfrag[q4 * 4 + 1] = kv.y;
                kfrag[q4 * 4 + 2] = kv.z; kfrag[q4 * 4 + 3] = kv.w;
            }
        }
#pragma unroll
        for (int row = 0; row < 16; ++row) {
            float p = 0.f;
            if (s < valid) {
#pragma unroll
                for (int dd = 0; dd < 16; ++dd) p += kfrag[dd] * qs[row][dpart * 16 + dd];
            }
            p += __shfl_xor(p, 1);
            p += __shfl_xor(p, 2);
            if (dpart == 0) sc[row][s] = (s < valid) ? p : -1e30f;
        }
    }
    __syncthreads();

    // ---- per-row partial softmax: wave w handles rows 4w..4w+3 ----
    const int wv = tid >> 6, lane = tid & 63;
    for (int rr = 0; rr < 4; ++rr) {
        const int row = wv * 4 + rr;
        const float v0 = sc[row][lane], v1 = sc[row][lane + 64];
        const float v2 = sc[row][lane + 128], v3 = sc[row][lane + 192];
        float m_ = fmaxf(fmaxf(v0, v1), fmaxf(v2, v3));
#pragma unroll
        for (int off = 32; off; off >>= 1) m_ = fmaxf(m_, __shfl_xor(m_, off));
        const float e0 = __expf(v0 - m_), e1 = __expf(v1 - m_);
        const float e2 = __expf(v2 - m_), e3 = __expf(v3 - m_);
        float l = e0 + e1 + e2 + e3;
#pragma unroll
        for (int off = 32; off; off >>= 1) l += __shfl_xor(l, off);
        sc[row][lane] = e0; sc[row][lane + 64] = e1;
        sc[row][lane + 128] = e2; sc[row][lane + 192] = e3;
        if (lane == 0) { mrow[row] = m_; lrow[row] = l; }
    }
    __syncthreads();

    // ---- O accumulation: d = tid&63, row-group = tid>>6 (4 rows each) ----
    const float* vbase = from_cache ? (cv + ((size_t)bg * S + (size_t)c * SC) * D)
                                    : (vfull + ((size_t)bg * ST + (size_t)c * SC) * D);
    float* vdst = vfull + ((size_t)bg * ST + (size_t)c * SC) * D;
    const int d = tid & 63, rg = tid >> 6;
    float oacc[4] = {0.f, 0.f, 0.f, 0.f};
    for (int s = 0; s < valid; ++s) {
        const float vvv = vbase[(size_t)s * D + d];
        if (from_cache && rg == 0) vdst[(size_t)s * D + d] = vvv;
#pragma unroll
        for (int j = 0; j < 4; ++j) oacc[j] += sc[rg * 4 + j][s] * vvv;
    }
#pragma unroll
    for (int j = 0; j < 4; ++j) {
        const int row = rg * 4 + j;
        o_part[(((size_t)bg * 16 + row) * NC + c) * 64 + d] = oacc[j];
    }
    if (tid < 16) {
        ml_part[(((size_t)bg * 16 + tid) * NC + c) * 2 + 0] = mrow[tid];
        ml_part[(((size_t)bg * 16 + tid) * NC + c) * 2 + 1] = lrow[tid];
    }
}

// ---------------- combine partials -> og (b,t,h,d) ----------------
__global__ __launch_bounds__(256) void attn_combine(const float* __restrict__ o_part,
                                                    const float* __restrict__ ml_part,
                                                    float* __restrict__ og) {
    const int gw = (blockIdx.x * 256 + threadIdx.x) >> 6;  // 0..1023 = bg*16 + row
    const int lane = threadIdx.x & 63;
    const int bg = gw >> 4, row = gw & 15;
    float M = -1e30f, L = 0.f, O = 0.f;
    for (int c = 0; c < NC; ++c) {
        const float m_ = ml_part[((size_t)gw * NC + c) * 2 + 0];
        const float l_ = ml_part[((size_t)gw * NC + c) * 2 + 1];
        const float o_ = o_part[((size_t)gw * NC + c) * 64 + lane];
        const float Mn = fmaxf(M, m_);
        const float fa = __expf(M - Mn), fb = __expf(m_ - Mn);
        O = O * fa + o_ * fb;
        L = L * fa + l_ * fb;
        M = Mn;
    }
    const float o = O / L;
    const int b = bg >> 3, g = bg & 7, r = row >> 2, t = row & 3;
    og[((size_t)(b * T + t) * H + (g * NREP + r)) * D + lane] = o;
}

extern "C" void kernel_launch(void* const* d_in, const int* in_sizes, int n_in,
                              void* d_out, int out_size, void* d_ws, size_t ws_size,
                              hipStream_t stream) {
    const float* x    = (const float*)d_in[0];
    const float* cosb = (const float*)d_in[1];
    const float* sinb = (const float*)d_in[2];
    const float* ck   = (const float*)d_in[3];
    const float* cv   = (const float*)d_in[4];
    const float* wq   = (const float*)d_in[5];
    const float* wk   = (const float*)d_in[6];
    const float* wvp  = (const float*)d_in[7];
    const float* wo   = (const float*)d_in[8];
    const float* qnw  = (const float*)d_in[9];
    const float* knw  = (const float*)d_in[10];

    float* out   = (float*)d_out;                       // [32][2048]
    float* kfull = out + 65536;                         // [B][HKV][ST][D]
    float* vfull = kfull + (size_t)B * HKV * ST * D;

    float* ws      = (float*)d_ws;
    float* q_raw   = ws;                    // 65536
    float* k_raw   = q_raw + 65536;         // 16384
    float* v_raw   = k_raw + 16384;         // 16384
    float* q_fin   = v_raw + 16384;         // 65536
    float* og      = q_fin + 65536;         // 65536
    float* o_part  = og + 65536;            // 64*16*NC*64 = 2162688
    float* ml_part = o_part + (size_t)64 * 16 * NC * 64;  // 67584

    // zero the atomic accumulators
    hipMemsetAsync(q_raw, 0, (size_t)(65536 + 16384 + 16384) * sizeof(float), stream);
    hipMemsetAsync(out, 0, (size_t)65536 * sizeof(float), stream);

    // projections
    gemm_splitk<<<dim3(2048 / 256, 2048 / KC), 256, 0, stream>>>(x, HID, wq, 2048, q_raw);
    gemm_splitk<<<dim3(512 / 256, 2048 / KC), 256, 0, stream>>>(x, HID, wk, 512, k_raw);
    gemm_splitk<<<dim3(512 / 256, 2048 / KC), 256, 0, stream>>>(x, HID, wvp, 512, v_raw);

    // rmsnorm + rope, scatter new K/V rows into k_full/v_full tails
    qkv_post<<<384, 256, 0, stream>>>(q_raw, k_raw, v_raw, cosb, sinb, qnw, knw,
                                      q_fin, kfull, vfull);

    // fused cache-copy + attention partials
    attn_part<<<dim3(64, NC), 256, 0, stream>>>(q_fin, ck, cv, kfull, vfull, o_part, ml_part);

    // combine
    attn_combine<<<256, 256, 0, stream>>>(o_part, ml_part, og);

    // output projection
    gemm_splitk<<<dim3(2048 / 256, 2048 / KC), 256, 0, stream>>>(og, 2048, wo, 2048, out);
}

// Round 2
// 537.509 us; speedup vs baseline: 2.7689x; 2.7689x over previous
//
#include <hip/hip_runtime.h>
#include <math.h>

#define B 8
#define T 4
#define HID 2048
#define H 32
#define HKV 8
#define D 64
#define S 8192
#define ST (S + T)            // 8196
#define NREP (H / HKV)        // 4
#define EPS 1e-6f
#define SCALE 0.125f          // D^-0.5

#define GM 32                 // GEMM rows (B*T)
#define SC 256                // attention S-chunk
#define NC ((ST + SC - 1) / SC)   // 33

// ---------------- GEMM v2: y[m,col] += x[m,k0..k0+127] @ W[k0..,col] ----------------
// block = 256 thr: ksub = tid&3 (4-way K split), cid = tid>>2 (64 col slots)
// cols per thread: col0 = bx*128+cid, col1 = col0+64. K-chunk = 128 (gridDim.y = 16).
// x^T staged in LDS [k][m] (pad 36 keeps float4 reads 16B-aligned); reads are
// lane-uniform broadcasts (conflict-free). Intra-wave shfl reduce over ksub, then
// one atomicAdd per (m, col) per block.
__global__ __launch_bounds__(256) void gemm_v2(const float* __restrict__ x, int ldx,
                                               const float* __restrict__ w, int N,
                                               float* __restrict__ y) {
    __shared__ float xs[128][36];
    const int tid = threadIdx.x;
    const int k0 = blockIdx.y * 128;

    // stage x^T: 32 rows x 128 k = 4096 floats; thread loads float4 along k
    for (int j = tid; j < 32 * 32; j += 256) {
        const int m = j >> 5;
        const int kk = (j & 31) * 4;
        const float4 xv = *(const float4*)&x[(size_t)m * ldx + k0 + kk];
        xs[kk + 0][m] = xv.x; xs[kk + 1][m] = xv.y;
        xs[kk + 2][m] = xv.z; xs[kk + 3][m] = xv.w;
    }
    __syncthreads();

    const int ksub = tid & 3, cid = tid >> 2;
    const int col0 = blockIdx.x * 128 + cid;
    const int col1 = col0 + 64;
    float acc0[GM], acc1[GM];
#pragma unroll
    for (int m = 0; m < GM; ++m) { acc0[m] = 0.f; acc1[m] = 0.f; }

    for (int ii = 0; ii < 32; ++ii) {
        const int kl = ksub * 32 + ii;
        const float w0 = w[(size_t)(k0 + kl) * N + col0];
        const float w1 = w[(size_t)(k0 + kl) * N + col1];
#pragma unroll
        for (int m4 = 0; m4 < GM; m4 += 4) {
            const float4 xv = *(const float4*)&xs[kl][m4];
            acc0[m4 + 0] += xv.x * w0; acc1[m4 + 0] += xv.x * w1;
            acc0[m4 + 1] += xv.y * w0; acc1[m4 + 1] += xv.y * w1;
            acc0[m4 + 2] += xv.z * w0; acc1[m4 + 2] += xv.z * w1;
            acc0[m4 + 3] += xv.w * w0; acc1[m4 + 3] += xv.w * w1;
        }
    }
    // reduce over ksub (lanes differing in bits 0..1)
#pragma unroll
    for (int m = 0; m < GM; ++m) {
        acc0[m] += __shfl_xor(acc0[m], 1); acc0[m] += __shfl_xor(acc0[m], 2);
        acc1[m] += __shfl_xor(acc1[m], 1); acc1[m] += __shfl_xor(acc1[m], 2);
    }
    if (ksub == 0) {
#pragma unroll
        for (int m = 0; m < GM; ++m) {
            atomicAdd(&y[(size_t)m * N + col0], acc0[m]);
            atomicAdd(&y[(size_t)m * N + col1], acc1[m]);
        }
    }
}

// ---------------- rmsnorm + rope on q,k; scatter new k,v into k_full/v_full ------
__global__ __launch_bounds__(256) void qkv_post(const float* __restrict__ q_raw,
                                                const float* __restrict__ k_raw,
                                                const float* __restrict__ v_raw,
                                                const float* __restrict__ cosb,
                                                const float* __restrict__ sinb,
                                                const float* __restrict__ qnw,
                                                const float* __restrict__ knw,
                                                float* __restrict__ q_fin,
                                                float* __restrict__ kfull,
                                                float* __restrict__ vfull) {
    const int wid = (blockIdx.x * 256 + threadIdx.x) >> 6;
    const int lane = threadIdx.x & 63;
    if (wid < 1024) {                       // q rows
        const int m = wid >> 5, h = wid & 31;
        float v = q_raw[(size_t)m * 2048 + h * 64 + lane];
        float ss = v * v;
#pragma unroll
        for (int off = 32; off; off >>= 1) ss += __shfl_xor(ss, off);
        float nv = qnw[lane] * v * rsqrtf(ss * (1.f / 64.f) + EPS);
        float other = __shfl_xor(nv, 32);
        float rot = (lane < 32) ? -other : other;
        float outv = nv * cosb[m * 64 + lane] + rot * sinb[m * 64 + lane];
        q_fin[(size_t)m * 2048 + h * 64 + lane] = outv * SCALE;
    } else if (wid < 1280) {                // k rows
        const int idx = wid - 1024;
        const int m = idx >> 3, g = idx & 7;
        float v = k_raw[(size_t)m * 512 + g * 64 + lane];
        float ss = v * v;
#pragma unroll
        for (int off = 32; off; off >>= 1) ss += __shfl_xor(ss, off);
        float nv = knw[lane] * v * rsqrtf(ss * (1.f / 64.f) + EPS);
        float other = __shfl_xor(nv, 32);
        float rot = (lane < 32) ? -other : other;
        float outv = nv * cosb[m * 64 + lane] + rot * sinb[m * 64 + lane];
        const int b = m >> 2, t = m & 3;
        kfull[((size_t)(b * HKV + g) * ST + S + t) * D + lane] = outv;
    } else if (wid < 1536) {                // v rows
        const int idx = wid - 1280;
        const int m = idx >> 3, g = idx & 7;
        float v = v_raw[(size_t)m * 512 + g * 64 + lane];
        const int b = m >> 2, t = m & 3;
        vfull[((size_t)(b * HKV + g) * ST + S + t) * D + lane] = v;
    }
}

// ---------------- fused cache-copy + attention partials ----------------
__global__ __launch_bounds__(256) void attn_part(const float* __restrict__ q_fin,
                                                 const float* __restrict__ ck,
                                                 const float* __restrict__ cv,
                                                 float* __restrict__ kfull,
                                                 float* __restrict__ vfull,
                                                 float* __restrict__ o_part,
                                                 float* __restrict__ ml_part) {
    const int bg = blockIdx.x;            // 0..63
    const int c  = blockIdx.y;            // 0..NC-1
    const int b = bg >> 3, g = bg & 7;
    const int tid = threadIdx.x;

    __shared__ float sc[16][SC];
    __shared__ float mrow[16], lrow[16];

    const int valid = min(SC, ST - c * SC);
    const bool from_cache = (c < S / SC);
    const float* kbase = from_cache ? (ck + ((size_t)bg * S + (size_t)c * SC) * D)
                                    : (kfull + ((size_t)bg * ST + (size_t)c * SC) * D);
    float* kdst = kfull + ((size_t)bg * ST + (size_t)c * SC) * D;

    // ---- phase 1: scores (q hoisted to registers) ----
    const int s_sub = tid >> 2;        // 0..63
    const int dpart = tid & 3;         // 0..3
    float qreg[16][16];
#pragma unroll
    for (int row = 0; row < 16; ++row) {
        const int r = row >> 2, t = row & 3;
        const float* qp = &q_fin[((size_t)(b * T + t) * H + (g * NREP + r)) * D + dpart * 16];
#pragma unroll
        for (int q4 = 0; q4 < 4; ++q4) {
            const float4 qv = *(const float4*)(qp + q4 * 4);
            qreg[row][q4 * 4 + 0] = qv.x; qreg[row][q4 * 4 + 1] = qv.y;
            qreg[row][q4 * 4 + 2] = qv.z; qreg[row][q4 * 4 + 3] = qv.w;
        }
    }

    for (int sg = 0; sg < SC; sg += 64) {
        const int s = sg + s_sub;
        const bool live = (s < valid);
        float kfrag[16];
        if (live) {
            const float4* kr = (const float4*)(kbase + (size_t)s * D + dpart * 16);
            float4* kw4 = (float4*)(kdst + (size_t)s * D + dpart * 16);
#pragma unroll
            for (int q4 = 0; q4 < 4; ++q4) {
                const float4 kv = kr[q4];
                if (from_cache) kw4[q4] = kv;
                kfrag[q4 * 4 + 0] = kv.x; kfrag[q4 * 4 + 1] = kv.y;
                kfrag[q4 * 4 + 2] = kv.z; kfrag[q4 * 4 + 3] = kv.w;
            }
        }
#pragma unroll
        for (int row = 0; row < 16; ++row) {
            float p = 0.f;
            if (live) {
#pragma unroll
                for (int dd = 0; dd < 16; ++dd) p += kfrag[dd] * qreg[row][dd];
            }
            p += __shfl_xor(p, 1);
            p += __shfl_xor(p, 2);
            if (dpart == 0) sc[row][s] = live ? p : -1e30f;
        }
    }
    __syncthreads();

    // ---- phase 2: per-row partial softmax ----
    const int wv_ = tid >> 6, lane = tid & 63;
    for (int rr = 0; rr < 4; ++rr) {
        const int row = wv_ * 4 + rr;
        const float v0 = sc[row][lane], v1 = sc[row][lane + 64];
        const float v2 = sc[row][lane + 128], v3 = sc[row][lane + 192];
        float m_ = fmaxf(fmaxf(v0, v1), fmaxf(v2, v3));
#pragma unroll
        for (int off = 32; off; off >>= 1) m_ = fmaxf(m_, __shfl_xor(m_, off));
        const float e0 = __expf(v0 - m_), e1 = __expf(v1 - m_);
        const float e2 = __expf(v2 - m_), e3 = __expf(v3 - m_);
        float l = e0 + e1 + e2 + e3;
#pragma unroll
        for (int off = 32; off; off >>= 1) l += __shfl_xor(l, off);
        sc[row][lane] = e0; sc[row][lane + 64] = e1;
        sc[row][lane + 128] = e2; sc[row][lane + 192] = e3;
        if (lane == 0) { mrow[row] = m_; lrow[row] = l; }
    }
    __syncthreads();

    // ---- phase 3: PV with float4 V loads ----
    // wave wv_ owns rows 4wv_..4wv_+3; lane: g4 = lane>>4 (s offset), d4 = lane&15 (d quad)
    const float* vbase = from_cache ? (cv + ((size_t)bg * S + (size_t)c * SC) * D)
                                    : (vfull + ((size_t)bg * ST + (size_t)c * SC) * D);
    float* vdst = vfull + ((size_t)bg * ST + (size_t)c * SC) * D;
    const int g4 = lane >> 4, d4 = lane & 15;
    float4 oacc[4];
#pragma unroll
    for (int j = 0; j < 4; ++j) { oacc[j].x = 0.f; oacc[j].y = 0.f; oacc[j].z = 0.f; oacc[j].w = 0.f; }

    for (int s0 = 0; s0 < SC; s0 += 4) {
        const int s = s0 + g4;
        if (s < valid) {
            const float4 vv = *(const float4*)&vbase[(size_t)s * D + d4 * 4];
            if (from_cache && wv_ == 0) *(float4*)&vdst[(size_t)s * D + d4 * 4] = vv;
#pragma unroll
            for (int j = 0; j < 4; ++j) {
                const float p = sc[wv_ * 4 + j][s];
                oacc[j].x += p * vv.x; oacc[j].y += p * vv.y;
                oacc[j].z += p * vv.z; oacc[j].w += p * vv.w;
            }
        }
    }
    // reduce across the 4 s-groups (lanes xor 16, 32)
#pragma unroll
    for (int j = 0; j < 4; ++j) {
        oacc[j].x += __shfl_xor(oacc[j].x, 16); oacc[j].y += __shfl_xor(oacc[j].y, 16);
        oacc[j].z += __shfl_xor(oacc[j].z, 16); oacc[j].w += __shfl_xor(oacc[j].w, 16);
        oacc[j].x += __shfl_xor(oacc[j].x, 32); oacc[j].y += __shfl_xor(oacc[j].y, 32);
        oacc[j].z += __shfl_xor(oacc[j].z, 32); oacc[j].w += __shfl_xor(oacc[j].w, 32);
    }
    if (g4 == 0) {
#pragma unroll
        for (int j = 0; j < 4; ++j) {
            const int row = wv_ * 4 + j;
            *(float4*)&o_part[(((size_t)bg * 16 + row) * NC + c) * 64 + d4 * 4] = oacc[j];
        }
    }
    if (tid < 16) {
        ml_part[(((size_t)bg * 16 + tid) * NC + c) * 2 + 0] = mrow[tid];
        ml_part[(((size_t)bg * 16 + tid) * NC + c) * 2 + 1] = lrow[tid];
    }
}

// ---------------- combine partials -> og (b,t,h,d) ----------------
__global__ __launch_bounds__(256) void attn_combine(const float* __restrict__ o_part,
                                                    const float* __restrict__ ml_part,
                                                    float* __restrict__ og) {
    const int gw = (blockIdx.x * 256 + threadIdx.x) >> 6;  // 0..1023
    const int lane = threadIdx.x & 63;
    const int bg = gw >> 4, row = gw & 15;
    float M = -1e30f, L = 0.f, O = 0.f;
    for (int c = 0; c < NC; ++c) {
        const float m_ = ml_part[((size_t)gw * NC + c) * 2 + 0];
        const float l_ = ml_part[((size_t)gw * NC + c) * 2 + 1];
        const float o_ = o_part[((size_t)gw * NC + c) * 64 + lane];
        const float Mn = fmaxf(M, m_);
        const float fa = __expf(M - Mn), fb = __expf(m_ - Mn);
        O = O * fa + o_ * fb;
        L = L * fa + l_ * fb;
        M = Mn;
    }
    const float o = O / L;
    const int b = bg >> 3, g = bg & 7, r = row >> 2, t = row & 3;
    og[((size_t)(b * T + t) * H + (g * NREP + r)) * D + lane] = o;
}

extern "C" void kernel_launch(void* const* d_in, const int* in_sizes, int n_in,
                              void* d_out, int out_size, void* d_ws, size_t ws_size,
                              hipStream_t stream) {
    const float* x    = (const float*)d_in[0];
    const float* cosb = (const float*)d_in[1];
    const float* sinb = (const float*)d_in[2];
    const float* ck   = (const float*)d_in[3];
    const float* cv   = (const float*)d_in[4];
    const float* wq   = (const float*)d_in[5];
    const float* wk   = (const float*)d_in[6];
    const float* wvp  = (const float*)d_in[7];
    const float* wo   = (const float*)d_in[8];
    const float* qnw  = (const float*)d_in[9];
    const float* knw  = (const float*)d_in[10];

    float* out   = (float*)d_out;                       // [32][2048]
    float* kfull = out + 65536;                         // [B][HKV][ST][D]
    float* vfull = kfull + (size_t)B * HKV * ST * D;

    float* ws      = (float*)d_ws;
    float* q_raw   = ws;                    // 65536
    float* k_raw   = q_raw + 65536;         // 16384
    float* v_raw   = k_raw + 16384;         // 16384
    float* q_fin   = v_raw + 16384;         // 65536
    float* og      = q_fin + 65536;         // 65536
    float* o_part  = og + 65536;            // 64*16*NC*64
    float* ml_part = o_part + (size_t)64 * 16 * NC * 64;

    // zero the atomic accumulators (q_raw,k_raw,v_raw contiguous) and out
    hipMemsetAsync(q_raw, 0, (size_t)(65536 + 16384 + 16384) * sizeof(float), stream);
    hipMemsetAsync(out, 0, (size_t)65536 * sizeof(float), stream);

    // projections (K = 2048 -> 16 chunks of 128)
    gemm_v2<<<dim3(2048 / 128, 16), 256, 0, stream>>>(x, HID, wq, 2048, q_raw);
    gemm_v2<<<dim3(512 / 128, 16), 256, 0, stream>>>(x, HID, wk, 512, k_raw);
    gemm_v2<<<dim3(512 / 128, 16), 256, 0, stream>>>(x, HID, wvp, 512, v_raw);

    // rmsnorm + rope, scatter new K/V rows
    qkv_post<<<384, 256, 0, stream>>>(q_raw, k_raw, v_raw, cosb, sinb, qnw, knw,
                                      q_fin, kfull, vfull);

    // fused cache-copy + attention partials
    attn_part<<<dim3(64, NC), 256, 0, stream>>>(q_fin, ck, cv, kfull, vfull, o_part, ml_part);

    // combine
    attn_combine<<<256, 256, 0, stream>>>(o_part, ml_part, og);

    // output projection
    gemm_v2<<<dim3(2048 / 128, 16), 256, 0, stream>>>(og, 2048, wo, 2048, out);
}

// Round 3
// 343.655 us; speedup vs baseline: 4.3308x; 1.5641x over previous
//
#include <hip/hip_runtime.h>
#include <math.h>

#define B 8
#define T 4
#define HID 2048
#define H 32
#define HKV 8
#define D 64
#define S 8192
#define ST (S + T)            // 8196
#define NREP (H / HKV)        // 4
#define EPS 1e-6f
#define SCALE 0.125f          // D^-0.5

#define GM 32                 // GEMM rows (B*T)
#define SC 256                // attention S-chunk
#define NC ((ST + SC - 1) / SC)   // 33

// ---------------- GEMM v2 (unchanged from round 2) ----------------
__global__ __launch_bounds__(256) void gemm_v2(const float* __restrict__ x, int ldx,
                                               const float* __restrict__ w, int N,
                                               float* __restrict__ y) {
    __shared__ float xs[128][36];
    const int tid = threadIdx.x;
    const int k0 = blockIdx.y * 128;

    for (int j = tid; j < 32 * 32; j += 256) {
        const int m = j >> 5;
        const int kk = (j & 31) * 4;
        const float4 xv = *(const float4*)&x[(size_t)m * ldx + k0 + kk];
        xs[kk + 0][m] = xv.x; xs[kk + 1][m] = xv.y;
        xs[kk + 2][m] = xv.z; xs[kk + 3][m] = xv.w;
    }
    __syncthreads();

    const int ksub = tid & 3, cid = tid >> 2;
    const int col0 = blockIdx.x * 128 + cid;
    const int col1 = col0 + 64;
    float acc0[GM], acc1[GM];
#pragma unroll
    for (int m = 0; m < GM; ++m) { acc0[m] = 0.f; acc1[m] = 0.f; }

    for (int ii = 0; ii < 32; ++ii) {
        const int kl = ksub * 32 + ii;
        const float w0 = w[(size_t)(k0 + kl) * N + col0];
        const float w1 = w[(size_t)(k0 + kl) * N + col1];
#pragma unroll
        for (int m4 = 0; m4 < GM; m4 += 4) {
            const float4 xv = *(const float4*)&xs[kl][m4];
            acc0[m4 + 0] += xv.x * w0; acc1[m4 + 0] += xv.x * w1;
            acc0[m4 + 1] += xv.y * w0; acc1[m4 + 1] += xv.y * w1;
            acc0[m4 + 2] += xv.z * w0; acc1[m4 + 2] += xv.z * w1;
            acc0[m4 + 3] += xv.w * w0; acc1[m4 + 3] += xv.w * w1;
        }
    }
#pragma unroll
    for (int m = 0; m < GM; ++m) {
        acc0[m] += __shfl_xor(acc0[m], 1); acc0[m] += __shfl_xor(acc0[m], 2);
        acc1[m] += __shfl_xor(acc1[m], 1); acc1[m] += __shfl_xor(acc1[m], 2);
    }
    if (ksub == 0) {
#pragma unroll
        for (int m = 0; m < GM; ++m) {
            atomicAdd(&y[(size_t)m * N + col0], acc0[m]);
            atomicAdd(&y[(size_t)m * N + col1], acc1[m]);
        }
    }
}

// ---------------- rmsnorm + rope (unchanged) ----------------
__global__ __launch_bounds__(256) void qkv_post(const float* __restrict__ q_raw,
                                                const float* __restrict__ k_raw,
                                                const float* __restrict__ v_raw,
                                                const float* __restrict__ cosb,
                                                const float* __restrict__ sinb,
                                                const float* __restrict__ qnw,
                                                const float* __restrict__ knw,
                                                float* __restrict__ q_fin,
                                                float* __restrict__ kfull,
                                                float* __restrict__ vfull) {
    const int wid = (blockIdx.x * 256 + threadIdx.x) >> 6;
    const int lane = threadIdx.x & 63;
    if (wid < 1024) {
        const int m = wid >> 5, h = wid & 31;
        float v = q_raw[(size_t)m * 2048 + h * 64 + lane];
        float ss = v * v;
#pragma unroll
        for (int off = 32; off; off >>= 1) ss += __shfl_xor(ss, off);
        float nv = qnw[lane] * v * rsqrtf(ss * (1.f / 64.f) + EPS);
        float other = __shfl_xor(nv, 32);
        float rot = (lane < 32) ? -other : other;
        float outv = nv * cosb[m * 64 + lane] + rot * sinb[m * 64 + lane];
        q_fin[(size_t)m * 2048 + h * 64 + lane] = outv * SCALE;
    } else if (wid < 1280) {
        const int idx = wid - 1024;
        const int m = idx >> 3, g = idx & 7;
        float v = k_raw[(size_t)m * 512 + g * 64 + lane];
        float ss = v * v;
#pragma unroll
        for (int off = 32; off; off >>= 1) ss += __shfl_xor(ss, off);
        float nv = knw[lane] * v * rsqrtf(ss * (1.f / 64.f) + EPS);
        float other = __shfl_xor(nv, 32);
        float rot = (lane < 32) ? -other : other;
        float outv = nv * cosb[m * 64 + lane] + rot * sinb[m * 64 + lane];
        const int b = m >> 2, t = m & 3;
        kfull[((size_t)(b * HKV + g) * ST + S + t) * D + lane] = outv;
    } else if (wid < 1536) {
        const int idx = wid - 1280;
        const int m = idx >> 3, g = idx & 7;
        float v = v_raw[(size_t)m * 512 + g * 64 + lane];
        const int b = m >> 2, t = m & 3;
        vfull[((size_t)(b * HKV + g) * ST + S + t) * D + lane] = v;
    }
}

// ---------------- fused cache-copy + attention partials v3 ----------------
__global__ __launch_bounds__(256) void attn_part(const float* __restrict__ q_fin,
                                                 const float* __restrict__ ck,
                                                 const float* __restrict__ cv,
                                                 float* __restrict__ kfull,
                                                 float* __restrict__ vfull,
                                                 float* __restrict__ o_part,
                                                 float* __restrict__ ml_part) {
    const int bg = blockIdx.x;            // 0..63
    const int c  = blockIdx.y;            // 0..NC-1
    const int b = bg >> 3, g = bg & 7;
    const int tid = threadIdx.x;

    __shared__ float qs[16][64];
    __shared__ float sc[16][SC];
    __shared__ float mrow[16], lrow[16];

    // q -> LDS (broadcast-read later; 2-way conflicts only)
    for (int j = tid; j < 16 * 64; j += 256) {
        const int row = j >> 6, d = j & 63;
        const int r = row >> 2, t = row & 3;
        qs[row][d] = q_fin[((size_t)(b * T + t) * H + (g * NREP + r)) * D + d];
    }
    __syncthreads();

    const bool from_cache = (c < S / SC);       // full chunk <=> from cache
    const int valid = from_cache ? SC : (ST - S);   // 256 or 4
    const float* kbase = from_cache ? (ck + ((size_t)bg * S + (size_t)c * SC) * D)
                                    : (kfull + ((size_t)bg * ST + (size_t)c * SC) * D);
    float* kdst = kfull + ((size_t)bg * ST + (size_t)c * SC) * D;

    const int s_sub = tid >> 2;        // 0..63
    const int dpart = tid & 3;         // 0..3

    // ---- phase 1: scores + K copy ----
    if (from_cache) {
        float4 kv[2][4];
        {
            const float4* kr = (const float4*)(kbase + (size_t)s_sub * D + dpart * 16);
            kv[0][0] = kr[0]; kv[0][1] = kr[1]; kv[0][2] = kr[2]; kv[0][3] = kr[3];
        }
#pragma unroll
        for (int pass = 0; pass < 4; ++pass) {
            const int cur = pass & 1, nxt = cur ^ 1;
            const int s = pass * 64 + s_sub;
            if (pass < 3) {
                const float4* kr = (const float4*)(kbase + (size_t)(s + 64) * D + dpart * 16);
                kv[nxt][0] = kr[0]; kv[nxt][1] = kr[1];
                kv[nxt][2] = kr[2]; kv[nxt][3] = kr[3];
            }
            float4* kw = (float4*)(kdst + (size_t)s * D + dpart * 16);
            kw[0] = kv[cur][0]; kw[1] = kv[cur][1];
            kw[2] = kv[cur][2]; kw[3] = kv[cur][3];
#pragma unroll
            for (int row = 0; row < 16; ++row) {
                const float4 q0 = *(const float4*)&qs[row][dpart * 16 + 0];
                const float4 q1 = *(const float4*)&qs[row][dpart * 16 + 4];
                const float4 q2 = *(const float4*)&qs[row][dpart * 16 + 8];
                const float4 q3 = *(const float4*)&qs[row][dpart * 16 + 12];
                float p = kv[cur][0].x * q0.x + kv[cur][0].y * q0.y
                        + kv[cur][0].z * q0.z + kv[cur][0].w * q0.w
                        + kv[cur][1].x * q1.x + kv[cur][1].y * q1.y
                        + kv[cur][1].z * q1.z + kv[cur][1].w * q1.w
                        + kv[cur][2].x * q2.x + kv[cur][2].y * q2.y
                        + kv[cur][2].z * q2.z + kv[cur][2].w * q2.w
                        + kv[cur][3].x * q3.x + kv[cur][3].y * q3.y
                        + kv[cur][3].z * q3.z + kv[cur][3].w * q3.w;
                p += __shfl_xor(p, 1);
                p += __shfl_xor(p, 2);
                if (dpart == 0) sc[row][s] = p;
            }
        }
    } else {
        // tail chunk: only `valid` (=4) rows, already resident in kfull
        for (int j = tid; j < 16 * SC; j += 256) (&sc[0][0])[j] = -1e30f;
        __syncthreads();
        const int s = s_sub;
        float kf[16];
        const bool live = (s < valid);
        if (live) {
            const float4* kr = (const float4*)(kbase + (size_t)s * D + dpart * 16);
#pragma unroll
            for (int q4 = 0; q4 < 4; ++q4) {
                const float4 kvv = kr[q4];
                kf[q4 * 4 + 0] = kvv.x; kf[q4 * 4 + 1] = kvv.y;
                kf[q4 * 4 + 2] = kvv.z; kf[q4 * 4 + 3] = kvv.w;
            }
        }
#pragma unroll
        for (int row = 0; row < 16; ++row) {
            float p = 0.f;
            if (live) {
#pragma unroll
                for (int dd = 0; dd < 16; ++dd) p += kf[dd] * qs[row][dpart * 16 + dd];
            }
            p += __shfl_xor(p, 1);
            p += __shfl_xor(p, 2);
            if (dpart == 0 && live) sc[row][s] = p;
        }
    }
    __syncthreads();

    // ---- phase 2: per-row partial softmax ----
    const int wv_ = tid >> 6, lane = tid & 63;
    for (int rr = 0; rr < 4; ++rr) {
        const int row = wv_ * 4 + rr;
        const float v0 = sc[row][lane], v1 = sc[row][lane + 64];
        const float v2 = sc[row][lane + 128], v3 = sc[row][lane + 192];
        float m_ = fmaxf(fmaxf(v0, v1), fmaxf(v2, v3));
#pragma unroll
        for (int off = 32; off; off >>= 1) m_ = fmaxf(m_, __shfl_xor(m_, off));
        const float e0 = __expf(v0 - m_), e1 = __expf(v1 - m_);
        const float e2 = __expf(v2 - m_), e3 = __expf(v3 - m_);
        float l = e0 + e1 + e2 + e3;
#pragma unroll
        for (int off = 32; off; off >>= 1) l += __shfl_xor(l, off);
        sc[row][lane] = e0; sc[row][lane + 64] = e1;
        sc[row][lane + 128] = e2; sc[row][lane + 192] = e3;
        if (lane == 0) { mrow[row] = m_; lrow[row] = l; }
    }
    __syncthreads();

    // ---- phase 3: PV + V copy (double-buffered float4) ----
    const float* vbase = from_cache ? (cv + ((size_t)bg * S + (size_t)c * SC) * D)
                                    : (vfull + ((size_t)bg * ST + (size_t)c * SC) * D);
    float* vdst = vfull + ((size_t)bg * ST + (size_t)c * SC) * D;
    const int g4 = lane >> 4, d4 = lane & 15;
    float4 oacc[4];
#pragma unroll
    for (int j = 0; j < 4; ++j) { oacc[j].x = 0.f; oacc[j].y = 0.f; oacc[j].z = 0.f; oacc[j].w = 0.f; }

    if (from_cache) {
        float4 vv[2];
        vv[0] = *(const float4*)&vbase[(size_t)g4 * D + d4 * 4];
#pragma unroll
        for (int it = 0; it < 64; ++it) {
            const int cur = it & 1, nxt = cur ^ 1;
            const int s = it * 4 + g4;
            if (it < 63) vv[nxt] = *(const float4*)&vbase[(size_t)(s + 4) * D + d4 * 4];
            if (wv_ == 0) *(float4*)&vdst[(size_t)s * D + d4 * 4] = vv[cur];
            const float p0 = sc[wv_ * 4 + 0][s];
            const float p1 = sc[wv_ * 4 + 1][s];
            const float p2 = sc[wv_ * 4 + 2][s];
            const float p3 = sc[wv_ * 4 + 3][s];
            oacc[0].x += p0 * vv[cur].x; oacc[0].y += p0 * vv[cur].y;
            oacc[0].z += p0 * vv[cur].z; oacc[0].w += p0 * vv[cur].w;
            oacc[1].x += p1 * vv[cur].x; oacc[1].y += p1 * vv[cur].y;
            oacc[1].z += p1 * vv[cur].z; oacc[1].w += p1 * vv[cur].w;
            oacc[2].x += p2 * vv[cur].x; oacc[2].y += p2 * vv[cur].y;
            oacc[2].z += p2 * vv[cur].z; oacc[2].w += p2 * vv[cur].w;
            oacc[3].x += p3 * vv[cur].x; oacc[3].y += p3 * vv[cur].y;
            oacc[3].z += p3 * vv[cur].z; oacc[3].w += p3 * vv[cur].w;
        }
    } else {
        for (int s = g4; s < valid; s += 4) {
            const float4 vvv = *(const float4*)&vbase[(size_t)s * D + d4 * 4];
            const float p0 = sc[wv_ * 4 + 0][s];
            const float p1 = sc[wv_ * 4 + 1][s];
            const float p2 = sc[wv_ * 4 + 2][s];
            const float p3 = sc[wv_ * 4 + 3][s];
            oacc[0].x += p0 * vvv.x; oacc[0].y += p0 * vvv.y;
            oacc[0].z += p0 * vvv.z; oacc[0].w += p0 * vvv.w;
            oacc[1].x += p1 * vvv.x; oacc[1].y += p1 * vvv.y;
            oacc[1].z += p1 * vvv.z; oacc[1].w += p1 * vvv.w;
            oacc[2].x += p2 * vvv.x; oacc[2].y += p2 * vvv.y;
            oacc[2].z += p2 * vvv.z; oacc[2].w += p2 * vvv.w;
            oacc[3].x += p3 * vvv.x; oacc[3].y += p3 * vvv.y;
            oacc[3].z += p3 * vvv.z; oacc[3].w += p3 * vvv.w;
        }
    }
    // reduce across the 4 s-groups (lanes xor 16, 32)
#pragma unroll
    for (int j = 0; j < 4; ++j) {
        oacc[j].x += __shfl_xor(oacc[j].x, 16); oacc[j].y += __shfl_xor(oacc[j].y, 16);
        oacc[j].z += __shfl_xor(oacc[j].z, 16); oacc[j].w += __shfl_xor(oacc[j].w, 16);
        oacc[j].x += __shfl_xor(oacc[j].x, 32); oacc[j].y += __shfl_xor(oacc[j].y, 32);
        oacc[j].z += __shfl_xor(oacc[j].z, 32); oacc[j].w += __shfl_xor(oacc[j].w, 32);
    }
    if (g4 == 0) {
#pragma unroll
        for (int j = 0; j < 4; ++j) {
            const int row = wv_ * 4 + j;
            *(float4*)&o_part[(((size_t)bg * 16 + row) * NC + c) * 64 + d4 * 4] = oacc[j];
        }
    }
    if (tid < 16) {
        ml_part[(((size_t)bg * 16 + tid) * NC + c) * 2 + 0] = mrow[tid];
        ml_part[(((size_t)bg * 16 + tid) * NC + c) * 2 + 1] = lrow[tid];
    }
}

// ---------------- combine partials (unchanged) ----------------
__global__ __launch_bounds__(256) void attn_combine(const float* __restrict__ o_part,
                                                    const float* __restrict__ ml_part,
                                                    float* __restrict__ og) {
    const int gw = (blockIdx.x * 256 + threadIdx.x) >> 6;  // 0..1023
    const int lane = threadIdx.x & 63;
    const int bg = gw >> 4, row = gw & 15;
    float M = -1e30f, L = 0.f, O = 0.f;
    for (int c = 0; c < NC; ++c) {
        const float m_ = ml_part[((size_t)gw * NC + c) * 2 + 0];
        const float l_ = ml_part[((size_t)gw * NC + c) * 2 + 1];
        const float o_ = o_part[((size_t)gw * NC + c) * 64 + lane];
        const float Mn = fmaxf(M, m_);
        const float fa = __expf(M - Mn), fb = __expf(m_ - Mn);
        O = O * fa + o_ * fb;
        L = L * fa + l_ * fb;
        M = Mn;
    }
    const float o = O / L;
    const int b = bg >> 3, g = bg & 7, r = row >> 2, t = row & 3;
    og[((size_t)(b * T + t) * H + (g * NREP + r)) * D + lane] = o;
}

extern "C" void kernel_launch(void* const* d_in, const int* in_sizes, int n_in,
                              void* d_out, int out_size, void* d_ws, size_t ws_size,
                              hipStream_t stream) {
    const float* x    = (const float*)d_in[0];
    const float* cosb = (const float*)d_in[1];
    const float* sinb = (const float*)d_in[2];
    const float* ck   = (const float*)d_in[3];
    const float* cv   = (const float*)d_in[4];
    const float* wq   = (const float*)d_in[5];
    const float* wk   = (const float*)d_in[6];
    const float* wvp  = (const float*)d_in[7];
    const float* wo   = (const float*)d_in[8];
    const float* qnw  = (const float*)d_in[9];
    const float* knw  = (const float*)d_in[10];

    float* out   = (float*)d_out;                       // [32][2048]
    float* kfull = out + 65536;                         // [B][HKV][ST][D]
    float* vfull = kfull + (size_t)B * HKV * ST * D;

    float* ws      = (float*)d_ws;
    float* q_raw   = ws;                    // 65536
    float* k_raw   = q_raw + 65536;         // 16384
    float* v_raw   = k_raw + 16384;         // 16384
    float* q_fin   = v_raw + 16384;         // 65536
    float* og      = q_fin + 65536;         // 65536
    float* o_part  = og + 65536;            // 64*16*NC*64
    float* ml_part = o_part + (size_t)64 * 16 * NC * 64;

    hipMemsetAsync(q_raw, 0, (size_t)(65536 + 16384 + 16384) * sizeof(float), stream);
    hipMemsetAsync(out, 0, (size_t)65536 * sizeof(float), stream);

    gemm_v2<<<dim3(2048 / 128, 16), 256, 0, stream>>>(x, HID, wq, 2048, q_raw);
    gemm_v2<<<dim3(512 / 128, 16), 256, 0, stream>>>(x, HID, wk, 512, k_raw);
    gemm_v2<<<dim3(512 / 128, 16), 256, 0, stream>>>(x, HID, wvp, 512, v_raw);

    qkv_post<<<384, 256, 0, stream>>>(q_raw, k_raw, v_raw, cosb, sinb, qnw, knw,
                                      q_fin, kfull, vfull);

    attn_part<<<dim3(64, NC), 256, 0, stream>>>(q_fin, ck, cv, kfull, vfull, o_part, ml_part);

    attn_combine<<<256, 256, 0, stream>>>(o_part, ml_part, og);

    gemm_v2<<<dim3(2048 / 128, 16), 256, 0, stream>>>(og, 2048, wo, 2048, out);
}

// Round 4
// 229.581 us; speedup vs baseline: 6.4826x; 1.4969x over previous
//
#include <hip/hip_runtime.h>
#include <math.h>

#define B 8
#define T 4
#define HID 2048
#define H 32
#define HKV 8
#define D 64
#define S 8192
#define ST (S + T)            // 8196
#define NREP (H / HKV)        // 4
#define EPS 1e-6f
#define SCALE 0.125f          // D^-0.5

#define GM 32                 // GEMM rows (B*T)
#define SC 256                // attention S-chunk
#define NC ((ST + SC - 1) / SC)   // 33
#define SCP 260               // padded LDS score row stride (f32)
#define PBP 272               // padded LDS P row stride (f16)

typedef __attribute__((ext_vector_type(8))) _Float16 half8;
typedef __attribute__((ext_vector_type(4))) float f32x4;

static __device__ __forceinline__ half8 cvt8(const float4 a, const float4 b) {
    half8 f;
    f[0] = (_Float16)a.x; f[1] = (_Float16)a.y; f[2] = (_Float16)a.z; f[3] = (_Float16)a.w;
    f[4] = (_Float16)b.x; f[5] = (_Float16)b.y; f[6] = (_Float16)b.z; f[7] = (_Float16)b.w;
    return f;
}

// ---------------- fused QKV projection GEMM (split-K, atomic accumulate) ---------
__global__ __launch_bounds__(256) void gemm_qkv(const float* __restrict__ x,
                                                const float* __restrict__ wq,
                                                const float* __restrict__ wk,
                                                const float* __restrict__ wv,
                                                float* __restrict__ q_raw,
                                                float* __restrict__ k_raw,
                                                float* __restrict__ v_raw) {
    __shared__ float xs[128][36];
    const int tid = threadIdx.x;
    const int k0 = blockIdx.y * 128;
    const int tile = blockIdx.x;

    const float* w; float* y; int N, colbase;
    if (tile < 16)      { w = wq; y = q_raw; N = 2048; colbase = tile * 128; }
    else if (tile < 20) { w = wk; y = k_raw; N = 512;  colbase = (tile - 16) * 128; }
    else                { w = wv; y = v_raw; N = 512;  colbase = (tile - 20) * 128; }

    for (int j = tid; j < 32 * 32; j += 256) {
        const int m = j >> 5;
        const int kk = (j & 31) * 4;
        const float4 xv = *(const float4*)&x[(size_t)m * HID + k0 + kk];
        xs[kk + 0][m] = xv.x; xs[kk + 1][m] = xv.y;
        xs[kk + 2][m] = xv.z; xs[kk + 3][m] = xv.w;
    }
    __syncthreads();

    const int ksub = tid & 3, cid = tid >> 2;
    const int col0 = colbase + cid;
    const int col1 = col0 + 64;
    float acc0[GM], acc1[GM];
#pragma unroll
    for (int m = 0; m < GM; ++m) { acc0[m] = 0.f; acc1[m] = 0.f; }

    for (int ii = 0; ii < 32; ++ii) {
        const int kl = ksub * 32 + ii;
        const float w0 = w[(size_t)(k0 + kl) * N + col0];
        const float w1 = w[(size_t)(k0 + kl) * N + col1];
#pragma unroll
        for (int m4 = 0; m4 < GM; m4 += 4) {
            const float4 xv = *(const float4*)&xs[kl][m4];
            acc0[m4 + 0] += xv.x * w0; acc1[m4 + 0] += xv.x * w1;
            acc0[m4 + 1] += xv.y * w0; acc1[m4 + 1] += xv.y * w1;
            acc0[m4 + 2] += xv.z * w0; acc1[m4 + 2] += xv.z * w1;
            acc0[m4 + 3] += xv.w * w0; acc1[m4 + 3] += xv.w * w1;
        }
    }
#pragma unroll
    for (int m = 0; m < GM; ++m) {
        acc0[m] += __shfl_xor(acc0[m], 1); acc0[m] += __shfl_xor(acc0[m], 2);
        acc1[m] += __shfl_xor(acc1[m], 1); acc1[m] += __shfl_xor(acc1[m], 2);
    }
    if (ksub == 0) {
#pragma unroll
        for (int m = 0; m < GM; ++m) {
            atomicAdd(&y[(size_t)m * N + col0], acc0[m]);
            atomicAdd(&y[(size_t)m * N + col1], acc1[m]);
        }
    }
}

// ---------------- standalone GEMM for the output projection ----------------
__global__ __launch_bounds__(256) void gemm_v2(const float* __restrict__ x, int ldx,
                                               const float* __restrict__ w, int N,
                                               float* __restrict__ y) {
    __shared__ float xs[128][36];
    const int tid = threadIdx.x;
    const int k0 = blockIdx.y * 128;

    for (int j = tid; j < 32 * 32; j += 256) {
        const int m = j >> 5;
        const int kk = (j & 31) * 4;
        const float4 xv = *(const float4*)&x[(size_t)m * ldx + k0 + kk];
        xs[kk + 0][m] = xv.x; xs[kk + 1][m] = xv.y;
        xs[kk + 2][m] = xv.z; xs[kk + 3][m] = xv.w;
    }
    __syncthreads();

    const int ksub = tid & 3, cid = tid >> 2;
    const int col0 = blockIdx.x * 128 + cid;
    const int col1 = col0 + 64;
    float acc0[GM], acc1[GM];
#pragma unroll
    for (int m = 0; m < GM; ++m) { acc0[m] = 0.f; acc1[m] = 0.f; }

    for (int ii = 0; ii < 32; ++ii) {
        const int kl = ksub * 32 + ii;
        const float w0 = w[(size_t)(k0 + kl) * N + col0];
        const float w1 = w[(size_t)(k0 + kl) * N + col1];
#pragma unroll
        for (int m4 = 0; m4 < GM; m4 += 4) {
            const float4 xv = *(const float4*)&xs[kl][m4];
            acc0[m4 + 0] += xv.x * w0; acc1[m4 + 0] += xv.x * w1;
            acc0[m4 + 1] += xv.y * w0; acc1[m4 + 1] += xv.y * w1;
            acc0[m4 + 2] += xv.z * w0; acc1[m4 + 2] += xv.z * w1;
            acc0[m4 + 3] += xv.w * w0; acc1[m4 + 3] += xv.w * w1;
        }
    }
#pragma unroll
    for (int m = 0; m < GM; ++m) {
        acc0[m] += __shfl_xor(acc0[m], 1); acc0[m] += __shfl_xor(acc0[m], 2);
        acc1[m] += __shfl_xor(acc1[m], 1); acc1[m] += __shfl_xor(acc1[m], 2);
    }
    if (ksub == 0) {
#pragma unroll
        for (int m = 0; m < GM; ++m) {
            atomicAdd(&y[(size_t)m * N + col0], acc0[m]);
            atomicAdd(&y[(size_t)m * N + col1], acc1[m]);
        }
    }
}

// ---------------- rmsnorm + rope (unchanged) ----------------
__global__ __launch_bounds__(256) void qkv_post(const float* __restrict__ q_raw,
                                                const float* __restrict__ k_raw,
                                                const float* __restrict__ v_raw,
                                                const float* __restrict__ cosb,
                                                const float* __restrict__ sinb,
                                                const float* __restrict__ qnw,
                                                const float* __restrict__ knw,
                                                float* __restrict__ q_fin,
                                                float* __restrict__ kfull,
                                                float* __restrict__ vfull) {
    const int wid = (blockIdx.x * 256 + threadIdx.x) >> 6;
    const int lane = threadIdx.x & 63;
    if (wid < 1024) {
        const int m = wid >> 5, h = wid & 31;
        float v = q_raw[(size_t)m * 2048 + h * 64 + lane];
        float ss = v * v;
#pragma unroll
        for (int off = 32; off; off >>= 1) ss += __shfl_xor(ss, off);
        float nv = qnw[lane] * v * rsqrtf(ss * (1.f / 64.f) + EPS);
        float other = __shfl_xor(nv, 32);
        float rot = (lane < 32) ? -other : other;
        float outv = nv * cosb[m * 64 + lane] + rot * sinb[m * 64 + lane];
        q_fin[(size_t)m * 2048 + h * 64 + lane] = outv * SCALE;
    } else if (wid < 1280) {
        const int idx = wid - 1024;
        const int m = idx >> 3, g = idx & 7;
        float v = k_raw[(size_t)m * 512 + g * 64 + lane];
        float ss = v * v;
#pragma unroll
        for (int off = 32; off; off >>= 1) ss += __shfl_xor(ss, off);
        float nv = knw[lane] * v * rsqrtf(ss * (1.f / 64.f) + EPS);
        float other = __shfl_xor(nv, 32);
        float rot = (lane < 32) ? -other : other;
        float outv = nv * cosb[m * 64 + lane] + rot * sinb[m * 64 + lane];
        const int b = m >> 2, t = m & 3;
        kfull[((size_t)(b * HKV + g) * ST + S + t) * D + lane] = outv;
    } else if (wid < 1536) {
        const int idx = wid - 1280;
        const int m = idx >> 3, g = idx & 7;
        float v = v_raw[(size_t)m * 512 + g * 64 + lane];
        const int b = m >> 2, t = m & 3;
        vfull[((size_t)(b * HKV + g) * ST + S + t) * D + lane] = v;
    }
}

// ---------------- fused cache-copy + attention partials (MFMA f16) ----------------
// MFMA 16x16x32 fragment maps (gfx950): A: m=lane&15, k=(lane>>4)*8+e
//                                       B: n=lane&15, k=(lane>>4)*8+e
//                                       C/D: col(n)=lane&15, row(m)=(lane>>4)*4+reg
__global__ __launch_bounds__(256) void attn_part(const float* __restrict__ q_fin,
                                                 const float* __restrict__ ck,
                                                 const float* __restrict__ cv,
                                                 float* __restrict__ kfull,
                                                 float* __restrict__ vfull,
                                                 float* __restrict__ o_part,
                                                 float* __restrict__ ml_part) {
    const int bg = blockIdx.x;            // 0..63
    const int c  = blockIdx.y;            // 0..NC-1
    const int b = bg >> 3, g = bg & 7;
    const int tid = threadIdx.x;
    const int lane = tid & 63;
    const int w = tid >> 6;               // wave 0..3
    const int q16 = lane & 15;
    const int kgrp = lane >> 4;           // 0..3

    __shared__ float sc[16][SCP];
    __shared__ __align__(16) _Float16 pb[16][PBP];
    __shared__ float mrow[16], lrow[16];

    const bool from_cache = (c < S / SC);
    const int valid = from_cache ? SC : (ST - S);   // 256 or 4
    const int vm1 = valid - 1;

    // ---- Q fragments (B-operand for QK^T): row q16, d = kgrp*8 + 32h ----
    half8 qf[2];
    {
        const float* qp = q_fin + ((size_t)(b * T + (q16 & 3)) * H + g * NREP + (q16 >> 2)) * D;
#pragma unroll
        for (int h = 0; h < 2; ++h) {
            const float* p = qp + h * 32 + kgrp * 8;
            qf[h] = cvt8(*(const float4*)p, *(const float4*)(p + 4));
        }
    }

    // ---- phase 1: QK^T via MFMA + fused K copy ----
    {
        const float* kb = from_cache ? (ck + ((size_t)bg * S + (size_t)c * SC) * D)
                                     : (kfull + ((size_t)bg * ST + (size_t)c * SC) * D);
        float* kd = kfull + ((size_t)bg * ST + (size_t)c * SC) * D;
#pragma unroll
        for (int t = 0; t < 4; ++t) {
            const int sl_raw = w * 64 + t * 16 + q16;          // A-frag row (chunk-local)
            const int sl = sl_raw <= vm1 ? sl_raw : vm1;       // clamp for tail
            const float* kp = kb + (size_t)sl * D + kgrp * 8;
            f32x4 acc = {0.f, 0.f, 0.f, 0.f};
#pragma unroll
            for (int h = 0; h < 2; ++h) {
                const float4 a = *(const float4*)(kp + h * 32);
                const float4 bb = *(const float4*)(kp + h * 32 + 4);
                if (from_cache) {
                    float* kw = kd + (size_t)sl * D + kgrp * 8 + h * 32;
                    *(float4*)kw = a;
                    *(float4*)(kw + 4) = bb;
                }
                acc = __builtin_amdgcn_mfma_f32_16x16x32_f16(cvt8(a, bb), qf[h], acc, 0, 0, 0);
            }
            const int sbase = w * 64 + t * 16 + kgrp * 4;
#pragma unroll
            for (int r = 0; r < 4; ++r)
                sc[q16][sbase + r] = (sbase + r <= vm1) ? acc[r] : -1e30f;
        }
    }
    __syncthreads();

    // ---- phase 2: per-row partial softmax; write P (f16) for PV ----
    for (int rr = 0; rr < 4; ++rr) {
        const int row = w * 4 + rr;
        const float v0 = sc[row][lane], v1 = sc[row][lane + 64];
        const float v2 = sc[row][lane + 128], v3 = sc[row][lane + 192];
        float m_ = fmaxf(fmaxf(v0, v1), fmaxf(v2, v3));
#pragma unroll
        for (int off = 32; off; off >>= 1) m_ = fmaxf(m_, __shfl_xor(m_, off));
        const float e0 = __expf(v0 - m_), e1 = __expf(v1 - m_);
        const float e2 = __expf(v2 - m_), e3 = __expf(v3 - m_);
        float l = e0 + e1 + e2 + e3;
#pragma unroll
        for (int off = 32; off; off >>= 1) l += __shfl_xor(l, off);
        pb[row][lane]       = (_Float16)e0;
        pb[row][lane + 64]  = (_Float16)e1;
        pb[row][lane + 128] = (_Float16)e2;
        pb[row][lane + 192] = (_Float16)e3;
        if (lane == 0) { mrow[row] = m_; lrow[row] = l; }
    }
    __syncthreads();

    // ---- phase 3: PV via MFMA + fused V copy. wave w owns d-slice [16w,16w+16) ----
    {
        const float* vb = from_cache ? (cv + ((size_t)bg * S + (size_t)c * SC) * D)
                                     : (vfull + ((size_t)bg * ST + (size_t)c * SC) * D);
        float* vd = vfull + ((size_t)bg * ST + (size_t)c * SC) * D;
        const int dglob = w * 16 + q16;       // B-frag n-index (d)
        f32x4 oacc = {0.f, 0.f, 0.f, 0.f};
#pragma unroll
        for (int ks = 0; ks < 8; ++ks) {
            const int s0 = ks * 32;
            const half8 pa = *(const half8*)&pb[q16][s0 + kgrp * 8];
            half8 vf;
#pragma unroll
            for (int e = 0; e < 8; ++e) {
                const int sr_raw = s0 + kgrp * 8 + e;
                const int sr = sr_raw <= vm1 ? sr_raw : vm1;
                const float vv = vb[(size_t)sr * D + dglob];
                if (from_cache) vd[(size_t)sr * D + dglob] = vv;
                vf[e] = (_Float16)vv;
            }
            oacc = __builtin_amdgcn_mfma_f32_16x16x32_f16(pa, vf, oacc, 0, 0, 0);
        }
#pragma unroll
        for (int r = 0; r < 4; ++r) {
            const int row = kgrp * 4 + r;     // q row (D m-index)
            o_part[(((size_t)bg * 16 + row) * NC + c) * 64 + dglob] = oacc[r];
        }
    }
    if (tid < 16) {
        ml_part[(((size_t)bg * 16 + tid) * NC + c) * 2 + 0] = mrow[tid];
        ml_part[(((size_t)bg * 16 + tid) * NC + c) * 2 + 1] = lrow[tid];
    }
}

// ---------------- combine partials (unchanged) ----------------
__global__ __launch_bounds__(256) void attn_combine(const float* __restrict__ o_part,
                                                    const float* __restrict__ ml_part,
                                                    float* __restrict__ og) {
    const int gw = (blockIdx.x * 256 + threadIdx.x) >> 6;  // 0..1023
    const int lane = threadIdx.x & 63;
    const int bg = gw >> 4, row = gw & 15;
    float M = -1e30f, L = 0.f, O = 0.f;
    for (int c = 0; c < NC; ++c) {
        const float m_ = ml_part[((size_t)gw * NC + c) * 2 + 0];
        const float l_ = ml_part[((size_t)gw * NC + c) * 2 + 1];
        const float o_ = o_part[((size_t)gw * NC + c) * 64 + lane];
        const float Mn = fmaxf(M, m_);
        const float fa = __expf(M - Mn), fb = __expf(m_ - Mn);
        O = O * fa + o_ * fb;
        L = L * fa + l_ * fb;
        M = Mn;
    }
    const float o = O / L;
    const int b = bg >> 3, g = bg & 7, r = row >> 2, t = row & 3;
    og[((size_t)(b * T + t) * H + (g * NREP + r)) * D + lane] = o;
}

extern "C" void kernel_launch(void* const* d_in, const int* in_sizes, int n_in,
                              void* d_out, int out_size, void* d_ws, size_t ws_size,
                              hipStream_t stream) {
    const float* x    = (const float*)d_in[0];
    const float* cosb = (const float*)d_in[1];
    const float* sinb = (const float*)d_in[2];
    const float* ck   = (const float*)d_in[3];
    const float* cv   = (const float*)d_in[4];
    const float* wq   = (const float*)d_in[5];
    const float* wk   = (const float*)d_in[6];
    const float* wvp  = (const float*)d_in[7];
    const float* wo   = (const float*)d_in[8];
    const float* qnw  = (const float*)d_in[9];
    const float* knw  = (const float*)d_in[10];

    float* out   = (float*)d_out;                       // [32][2048]
    float* kfull = out + 65536;                         // [B][HKV][ST][D]
    float* vfull = kfull + (size_t)B * HKV * ST * D;

    float* ws      = (float*)d_ws;
    float* q_raw   = ws;                    // 65536
    float* k_raw   = q_raw + 65536;         // 16384
    float* v_raw   = k_raw + 16384;         // 16384
    float* q_fin   = v_raw + 16384;         // 65536
    float* og      = q_fin + 65536;         // 65536
    float* o_part  = og + 65536;            // 64*16*NC*64
    float* ml_part = o_part + (size_t)64 * 16 * NC * 64;

    hipMemsetAsync(q_raw, 0, (size_t)(65536 + 16384 + 16384) * sizeof(float), stream);
    hipMemsetAsync(out, 0, (size_t)65536 * sizeof(float), stream);

    // fused q/k/v projections (one dispatch)
    gemm_qkv<<<dim3(24, 16), 256, 0, stream>>>(x, wq, wk, wvp, q_raw, k_raw, v_raw);

    qkv_post<<<384, 256, 0, stream>>>(q_raw, k_raw, v_raw, cosb, sinb, qnw, knw,
                                      q_fin, kfull, vfull);

    attn_part<<<dim3(64, NC), 256, 0, stream>>>(q_fin, ck, cv, kfull, vfull, o_part, ml_part);

    attn_combine<<<256, 256, 0, stream>>>(o_part, ml_part, og);

    gemm_v2<<<dim3(2048 / 128, 16), 256, 0, stream>>>(og, 2048, wo, 2048, out);
}

// Round 5
// 204.012 us; speedup vs baseline: 7.2951x; 1.1253x over previous
//
#include <hip/hip_runtime.h>
#include <math.h>

#define B 8
#define T 4
#define HID 2048
#define H 32
#define HKV 8
#define D 64
#define S 8192
#define ST (S + T)            // 8196
#define NREP (H / HKV)        // 4
#define EPS 1e-6f
#define SCALE 0.125f          // D^-0.5

#define GM 32                 // GEMM rows (B*T)
#define SC 128                // attention S-chunk
#define NC ((ST + SC - 1) / SC)   // 65 (64 full + 4-row tail)
#define SCP 132               // padded LDS score row stride (f32)
#define PBP 136               // padded LDS P row stride (f16)

typedef __attribute__((ext_vector_type(8))) _Float16 half8;
typedef __attribute__((ext_vector_type(4))) float f32x4;

static __device__ __forceinline__ half8 cvt8(const float4 a, const float4 b) {
    half8 f;
    f[0] = (_Float16)a.x; f[1] = (_Float16)a.y; f[2] = (_Float16)a.z; f[3] = (_Float16)a.w;
    f[4] = (_Float16)b.x; f[5] = (_Float16)b.y; f[6] = (_Float16)b.z; f[7] = (_Float16)b.w;
    return f;
}

// ---------------- fused QKV projection GEMM (split-K, atomic accumulate) ---------
__global__ __launch_bounds__(256) void gemm_qkv(const float* __restrict__ x,
                                                const float* __restrict__ wq,
                                                const float* __restrict__ wk,
                                                const float* __restrict__ wv,
                                                float* __restrict__ q_raw,
                                                float* __restrict__ k_raw,
                                                float* __restrict__ v_raw) {
    __shared__ float xs[128][36];
    const int tid = threadIdx.x;
    const int k0 = blockIdx.y * 128;
    const int tile = blockIdx.x;

    const float* w; float* y; int N, colbase;
    if (tile < 16)      { w = wq; y = q_raw; N = 2048; colbase = tile * 128; }
    else if (tile < 20) { w = wk; y = k_raw; N = 512;  colbase = (tile - 16) * 128; }
    else                { w = wv; y = v_raw; N = 512;  colbase = (tile - 20) * 128; }

    for (int j = tid; j < 32 * 32; j += 256) {
        const int m = j >> 5;
        const int kk = (j & 31) * 4;
        const float4 xv = *(const float4*)&x[(size_t)m * HID + k0 + kk];
        xs[kk + 0][m] = xv.x; xs[kk + 1][m] = xv.y;
        xs[kk + 2][m] = xv.z; xs[kk + 3][m] = xv.w;
    }
    __syncthreads();

    const int ksub = tid & 3, cid = tid >> 2;
    const int col0 = colbase + cid;
    const int col1 = col0 + 64;
    float acc0[GM], acc1[GM];
#pragma unroll
    for (int m = 0; m < GM; ++m) { acc0[m] = 0.f; acc1[m] = 0.f; }

    for (int ii = 0; ii < 32; ++ii) {
        const int kl = ksub * 32 + ii;
        const float w0 = w[(size_t)(k0 + kl) * N + col0];
        const float w1 = w[(size_t)(k0 + kl) * N + col1];
#pragma unroll
        for (int m4 = 0; m4 < GM; m4 += 4) {
            const float4 xv = *(const float4*)&xs[kl][m4];
            acc0[m4 + 0] += xv.x * w0; acc1[m4 + 0] += xv.x * w1;
            acc0[m4 + 1] += xv.y * w0; acc1[m4 + 1] += xv.y * w1;
            acc0[m4 + 2] += xv.z * w0; acc1[m4 + 2] += xv.z * w1;
            acc0[m4 + 3] += xv.w * w0; acc1[m4 + 3] += xv.w * w1;
        }
    }
#pragma unroll
    for (int m = 0; m < GM; ++m) {
        acc0[m] += __shfl_xor(acc0[m], 1); acc0[m] += __shfl_xor(acc0[m], 2);
        acc1[m] += __shfl_xor(acc1[m], 1); acc1[m] += __shfl_xor(acc1[m], 2);
    }
    if (ksub == 0) {
#pragma unroll
        for (int m = 0; m < GM; ++m) {
            atomicAdd(&y[(size_t)m * N + col0], acc0[m]);
            atomicAdd(&y[(size_t)m * N + col1], acc1[m]);
        }
    }
}

// ---------------- standalone GEMM for the output projection ----------------
__global__ __launch_bounds__(256) void gemm_v2(const float* __restrict__ x, int ldx,
                                               const float* __restrict__ w, int N,
                                               float* __restrict__ y) {
    __shared__ float xs[128][36];
    const int tid = threadIdx.x;
    const int k0 = blockIdx.y * 128;

    for (int j = tid; j < 32 * 32; j += 256) {
        const int m = j >> 5;
        const int kk = (j & 31) * 4;
        const float4 xv = *(const float4*)&x[(size_t)m * ldx + k0 + kk];
        xs[kk + 0][m] = xv.x; xs[kk + 1][m] = xv.y;
        xs[kk + 2][m] = xv.z; xs[kk + 3][m] = xv.w;
    }
    __syncthreads();

    const int ksub = tid & 3, cid = tid >> 2;
    const int col0 = blockIdx.x * 128 + cid;
    const int col1 = col0 + 64;
    float acc0[GM], acc1[GM];
#pragma unroll
    for (int m = 0; m < GM; ++m) { acc0[m] = 0.f; acc1[m] = 0.f; }

    for (int ii = 0; ii < 32; ++ii) {
        const int kl = ksub * 32 + ii;
        const float w0 = w[(size_t)(k0 + kl) * N + col0];
        const float w1 = w[(size_t)(k0 + kl) * N + col1];
#pragma unroll
        for (int m4 = 0; m4 < GM; m4 += 4) {
            const float4 xv = *(const float4*)&xs[kl][m4];
            acc0[m4 + 0] += xv.x * w0; acc1[m4 + 0] += xv.x * w1;
            acc0[m4 + 1] += xv.y * w0; acc1[m4 + 1] += xv.y * w1;
            acc0[m4 + 2] += xv.z * w0; acc1[m4 + 2] += xv.z * w1;
            acc0[m4 + 3] += xv.w * w0; acc1[m4 + 3] += xv.w * w1;
        }
    }
#pragma unroll
    for (int m = 0; m < GM; ++m) {
        acc0[m] += __shfl_xor(acc0[m], 1); acc0[m] += __shfl_xor(acc0[m], 2);
        acc1[m] += __shfl_xor(acc1[m], 1); acc1[m] += __shfl_xor(acc1[m], 2);
    }
    if (ksub == 0) {
#pragma unroll
        for (int m = 0; m < GM; ++m) {
            atomicAdd(&y[(size_t)m * N + col0], acc0[m]);
            atomicAdd(&y[(size_t)m * N + col1], acc1[m]);
        }
    }
}

// ---------------- rmsnorm + rope (unchanged) ----------------
__global__ __launch_bounds__(256) void qkv_post(const float* __restrict__ q_raw,
                                                const float* __restrict__ k_raw,
                                                const float* __restrict__ v_raw,
                                                const float* __restrict__ cosb,
                                                const float* __restrict__ sinb,
                                                const float* __restrict__ qnw,
                                                const float* __restrict__ knw,
                                                float* __restrict__ q_fin,
                                                float* __restrict__ kfull,
                                                float* __restrict__ vfull) {
    const int wid = (blockIdx.x * 256 + threadIdx.x) >> 6;
    const int lane = threadIdx.x & 63;
    if (wid < 1024) {
        const int m = wid >> 5, h = wid & 31;
        float v = q_raw[(size_t)m * 2048 + h * 64 + lane];
        float ss = v * v;
#pragma unroll
        for (int off = 32; off; off >>= 1) ss += __shfl_xor(ss, off);
        float nv = qnw[lane] * v * rsqrtf(ss * (1.f / 64.f) + EPS);
        float other = __shfl_xor(nv, 32);
        float rot = (lane < 32) ? -other : other;
        float outv = nv * cosb[m * 64 + lane] + rot * sinb[m * 64 + lane];
        q_fin[(size_t)m * 2048 + h * 64 + lane] = outv * SCALE;
    } else if (wid < 1280) {
        const int idx = wid - 1024;
        const int m = idx >> 3, g = idx & 7;
        float v = k_raw[(size_t)m * 512 + g * 64 + lane];
        float ss = v * v;
#pragma unroll
        for (int off = 32; off; off >>= 1) ss += __shfl_xor(ss, off);
        float nv = knw[lane] * v * rsqrtf(ss * (1.f / 64.f) + EPS);
        float other = __shfl_xor(nv, 32);
        float rot = (lane < 32) ? -other : other;
        float outv = nv * cosb[m * 64 + lane] + rot * sinb[m * 64 + lane];
        const int b = m >> 2, t = m & 3;
        kfull[((size_t)(b * HKV + g) * ST + S + t) * D + lane] = outv;
    } else if (wid < 1536) {
        const int idx = wid - 1280;
        const int m = idx >> 3, g = idx & 7;
        float v = v_raw[(size_t)m * 512 + g * 64 + lane];
        const int b = m >> 2, t = m & 3;
        vfull[((size_t)(b * HKV + g) * ST + S + t) * D + lane] = v;
    }
}

// ---------------- fused cache-copy + attention partials (MFMA f16, SC=128) -------
// MFMA 16x16x32 fragment maps (gfx950): A: m=lane&15, k=(lane>>4)*8+e
//                                       B: n=lane&15, k=(lane>>4)*8+e
//                                       C/D: col(n)=lane&15, row(m)=(lane>>4)*4+reg
__global__ __launch_bounds__(256) void attn_part(const float* __restrict__ q_fin,
                                                 const float* __restrict__ ck,
                                                 const float* __restrict__ cv,
                                                 float* __restrict__ kfull,
                                                 float* __restrict__ vfull,
                                                 float* __restrict__ o_part,
                                                 float* __restrict__ ml_part) {
    const int bg = blockIdx.x;            // 0..63
    const int c  = blockIdx.y;            // 0..NC-1
    const int b = bg >> 3, g = bg & 7;
    const int tid = threadIdx.x;
    const int lane = tid & 63;
    const int w = tid >> 6;               // wave 0..3
    const int q16 = lane & 15;
    const int kgrp = lane >> 4;           // 0..3

    __shared__ __align__(16) float sc[16][SCP];
    __shared__ __align__(16) _Float16 pb[16][PBP];
    __shared__ float mrow[16], lrow[16];

    const bool from_cache = (c < S / SC);
    const int valid = from_cache ? SC : (ST - S);   // 128 or 4
    const int vm1 = valid - 1;

    // ---- Q fragments (B-operand for QK^T): row q16, d = kgrp*8 + 32h ----
    half8 qf[2];
    {
        const float* qp = q_fin + ((size_t)(b * T + (q16 & 3)) * H + g * NREP + (q16 >> 2)) * D;
#pragma unroll
        for (int h = 0; h < 2; ++h) {
            const float* p = qp + h * 32 + kgrp * 8;
            qf[h] = cvt8(*(const float4*)p, *(const float4*)(p + 4));
        }
    }

    // ---- phase 1: QK^T via MFMA + fused K copy ----
    {
        const float* kb = from_cache ? (ck + ((size_t)bg * S + (size_t)c * SC) * D)
                                     : (kfull + ((size_t)bg * ST + (size_t)c * SC) * D);
        float* kd = kfull + ((size_t)bg * ST + (size_t)c * SC) * D;
#pragma unroll
        for (int t = 0; t < 2; ++t) {
            const int sl_raw = w * 32 + t * 16 + q16;          // A-frag row (chunk-local)
            const int sl = min(sl_raw, vm1);                   // clamp for tail
            const float* kp = kb + (size_t)sl * D + kgrp * 8;
            f32x4 acc = {0.f, 0.f, 0.f, 0.f};
#pragma unroll
            for (int h = 0; h < 2; ++h) {
                const float4 a = *(const float4*)(kp + h * 32);
                const float4 bb = *(const float4*)(kp + h * 32 + 4);
                if (from_cache) {
                    float* kw = kd + (size_t)sl * D + kgrp * 8 + h * 32;
                    *(float4*)kw = a;
                    *(float4*)(kw + 4) = bb;
                }
                acc = __builtin_amdgcn_mfma_f32_16x16x32_f16(cvt8(a, bb), qf[h], acc, 0, 0, 0);
            }
            const int sbase = w * 32 + t * 16 + kgrp * 4;
            if (sbase + 3 <= vm1) {
                *(f32x4*)&sc[q16][sbase] = acc;
            } else {
#pragma unroll
                for (int r = 0; r < 4; ++r)
                    sc[q16][sbase + r] = (sbase + r <= vm1) ? acc[r] : -1e30f;
            }
        }
    }
    __syncthreads();

    // ---- phase 2: per-row partial softmax; write P (f16) for PV ----
    for (int rr = 0; rr < 4; ++rr) {
        const int row = w * 4 + rr;
        const float v0 = sc[row][lane], v1 = sc[row][lane + 64];
        float m_ = fmaxf(v0, v1);
#pragma unroll
        for (int off = 32; off; off >>= 1) m_ = fmaxf(m_, __shfl_xor(m_, off));
        const float e0 = __expf(v0 - m_), e1 = __expf(v1 - m_);
        float l = e0 + e1;
#pragma unroll
        for (int off = 32; off; off >>= 1) l += __shfl_xor(l, off);
        pb[row][lane]      = (_Float16)e0;
        pb[row][lane + 64] = (_Float16)e1;
        if (lane == 0) { mrow[row] = m_; lrow[row] = l; }
    }
    __syncthreads();

    // ---- phase 3: PV via MFMA + fused V copy. wave w owns d-slice [16w,16w+16) ----
    {
        const float* vb = from_cache ? (cv + ((size_t)bg * S + (size_t)c * SC) * D)
                                     : (vfull + ((size_t)bg * ST + (size_t)c * SC) * D);
        float* vd = vfull + ((size_t)bg * ST + (size_t)c * SC) * D;
        const int dglob = w * 16 + q16;       // B-frag n-index (d)
        f32x4 oacc = {0.f, 0.f, 0.f, 0.f};
#pragma unroll
        for (int ks = 0; ks < 4; ++ks) {
            const int s0 = ks * 32;
            const half8 pa = *(const half8*)&pb[q16][s0 + kgrp * 8];
            half8 vf;
#pragma unroll
            for (int e = 0; e < 8; ++e) {
                const int sr = min(s0 + kgrp * 8 + e, vm1);
                const float vv = vb[(size_t)sr * D + dglob];
                if (from_cache) vd[(size_t)sr * D + dglob] = vv;
                vf[e] = (_Float16)vv;
            }
            oacc = __builtin_amdgcn_mfma_f32_16x16x32_f16(pa, vf, oacc, 0, 0, 0);
        }
#pragma unroll
        for (int r = 0; r < 4; ++r) {
            const int row = kgrp * 4 + r;     // q row (D m-index)
            o_part[(((size_t)bg * 16 + row) * NC + c) * 64 + dglob] = oacc[r];
        }
    }
    if (tid < 16) {
        ml_part[(((size_t)bg * 16 + tid) * NC + c) * 2 + 0] = mrow[tid];
        ml_part[(((size_t)bg * 16 + tid) * NC + c) * 2 + 1] = lrow[tid];
    }
}

// ---------------- combine partials (unchanged structure) ----------------
__global__ __launch_bounds__(256) void attn_combine(const float* __restrict__ o_part,
                                                    const float* __restrict__ ml_part,
                                                    float* __restrict__ og) {
    const int gw = (blockIdx.x * 256 + threadIdx.x) >> 6;  // 0..1023
    const int lane = threadIdx.x & 63;
    const int bg = gw >> 4, row = gw & 15;
    float M = -1e30f, L = 0.f, O = 0.f;
    for (int c = 0; c < NC; ++c) {
        const float m_ = ml_part[((size_t)gw * NC + c) * 2 + 0];
        const float l_ = ml_part[((size_t)gw * NC + c) * 2 + 1];
        const float o_ = o_part[((size_t)gw * NC + c) * 64 + lane];
        const float Mn = fmaxf(M, m_);
        const float fa = __expf(M - Mn), fb = __expf(m_ - Mn);
        O = O * fa + o_ * fb;
        L = L * fa + l_ * fb;
        M = Mn;
    }
    const float o = O / L;
    const int b = bg >> 3, g = bg & 7, r = row >> 2, t = row & 3;
    og[((size_t)(b * T + t) * H + (g * NREP + r)) * D + lane] = o;
}

extern "C" void kernel_launch(void* const* d_in, const int* in_sizes, int n_in,
                              void* d_out, int out_size, void* d_ws, size_t ws_size,
                              hipStream_t stream) {
    const float* x    = (const float*)d_in[0];
    const float* cosb = (const float*)d_in[1];
    const float* sinb = (const float*)d_in[2];
    const float* ck   = (const float*)d_in[3];
    const float* cv   = (const float*)d_in[4];
    const float* wq   = (const float*)d_in[5];
    const float* wk   = (const float*)d_in[6];
    const float* wvp  = (const float*)d_in[7];
    const float* wo   = (const float*)d_in[8];
    const float* qnw  = (const float*)d_in[9];
    const float* knw  = (const float*)d_in[10];

    float* out   = (float*)d_out;                       // [32][2048]
    float* kfull = out + 65536;                         // [B][HKV][ST][D]
    float* vfull = kfull + (size_t)B * HKV * ST * D;

    float* ws      = (float*)d_ws;
    float* q_raw   = ws;                    // 65536
    float* k_raw   = q_raw + 65536;         // 16384
    float* v_raw   = k_raw + 16384;         // 16384
    float* q_fin   = v_raw + 16384;         // 65536
    float* og      = q_fin + 65536;         // 65536
    float* o_part  = og + 65536;            // 64*16*NC*64
    float* ml_part = o_part + (size_t)64 * 16 * NC * 64;

    hipMemsetAsync(q_raw, 0, (size_t)(65536 + 16384 + 16384) * sizeof(float), stream);
    hipMemsetAsync(out, 0, (size_t)65536 * sizeof(float), stream);

    // fused q/k/v projections (one dispatch)
    gemm_qkv<<<dim3(24, 16), 256, 0, stream>>>(x, wq, wk, wvp, q_raw, k_raw, v_raw);

    qkv_post<<<384, 256, 0, stream>>>(q_raw, k_raw, v_raw, cosb, sinb, qnw, knw,
                                      q_fin, kfull, vfull);

    attn_part<<<dim3(64, NC), 256, 0, stream>>>(q_fin, ck, cv, kfull, vfull, o_part, ml_part);

    attn_combine<<<256, 256, 0, stream>>>(o_part, ml_part, og);

    gemm_v2<<<dim3(2048 / 128, 16), 256, 0, stream>>>(og, 2048, wo, 2048, out);
}

// Round 6
// 190.804 us; speedup vs baseline: 7.8001x; 1.0692x over previous
//
#include <hip/hip_runtime.h>
#include <math.h>

#define B 8
#define T 4
#define HID 2048
#define H 32
#define HKV 8
#define D 64
#define S 8192
#define ST (S + T)            // 8196
#define NREP (H / HKV)        // 4
#define EPS 1e-6f
#define SCALE 0.125f          // D^-0.5

#define GM 32                 // GEMM rows (B*T)
#define SC 128                // attention S-chunk
#define NC ((ST + SC - 1) / SC)   // 65 (64 full + 4-row tail)
#define SCP 132               // padded LDS score row stride (f32)
#define PBP 136               // padded LDS P row stride (f16)

typedef __attribute__((ext_vector_type(8))) _Float16 half8;
typedef __attribute__((ext_vector_type(4))) float f32x4;

static __device__ __forceinline__ half8 cvt8(const float4 a, const float4 b) {
    half8 f;
    f[0] = (_Float16)a.x; f[1] = (_Float16)a.y; f[2] = (_Float16)a.z; f[3] = (_Float16)a.w;
    f[4] = (_Float16)b.x; f[5] = (_Float16)b.y; f[6] = (_Float16)b.z; f[7] = (_Float16)b.w;
    return f;
}

// ---------------- fused QKV projection GEMM (split-K, atomic accumulate) ---------
__global__ __launch_bounds__(256) void gemm_qkv(const float* __restrict__ x,
                                                const float* __restrict__ wq,
                                                const float* __restrict__ wk,
                                                const float* __restrict__ wv,
                                                float* __restrict__ q_raw,
                                                float* __restrict__ k_raw,
                                                float* __restrict__ v_raw) {
    __shared__ float xs[128][36];
    const int tid = threadIdx.x;
    const int k0 = blockIdx.y * 128;
    const int tile = blockIdx.x;

    const float* w; float* y; int N, colbase;
    if (tile < 16)      { w = wq; y = q_raw; N = 2048; colbase = tile * 128; }
    else if (tile < 20) { w = wk; y = k_raw; N = 512;  colbase = (tile - 16) * 128; }
    else                { w = wv; y = v_raw; N = 512;  colbase = (tile - 20) * 128; }

    for (int j = tid; j < 32 * 32; j += 256) {
        const int m = j >> 5;
        const int kk = (j & 31) * 4;
        const float4 xv = *(const float4*)&x[(size_t)m * HID + k0 + kk];
        xs[kk + 0][m] = xv.x; xs[kk + 1][m] = xv.y;
        xs[kk + 2][m] = xv.z; xs[kk + 3][m] = xv.w;
    }
    __syncthreads();

    const int ksub = tid & 3, cid = tid >> 2;
    const int col0 = colbase + cid;
    const int col1 = col0 + 64;
    float acc0[GM], acc1[GM];
#pragma unroll
    for (int m = 0; m < GM; ++m) { acc0[m] = 0.f; acc1[m] = 0.f; }

    for (int ii = 0; ii < 32; ++ii) {
        const int kl = ksub * 32 + ii;
        const float w0 = w[(size_t)(k0 + kl) * N + col0];
        const float w1 = w[(size_t)(k0 + kl) * N + col1];
#pragma unroll
        for (int m4 = 0; m4 < GM; m4 += 4) {
            const float4 xv = *(const float4*)&xs[kl][m4];
            acc0[m4 + 0] += xv.x * w0; acc1[m4 + 0] += xv.x * w1;
            acc0[m4 + 1] += xv.y * w0; acc1[m4 + 1] += xv.y * w1;
            acc0[m4 + 2] += xv.z * w0; acc1[m4 + 2] += xv.z * w1;
            acc0[m4 + 3] += xv.w * w0; acc1[m4 + 3] += xv.w * w1;
        }
    }
#pragma unroll
    for (int m = 0; m < GM; ++m) {
        acc0[m] += __shfl_xor(acc0[m], 1); acc0[m] += __shfl_xor(acc0[m], 2);
        acc1[m] += __shfl_xor(acc1[m], 1); acc1[m] += __shfl_xor(acc1[m], 2);
    }
    if (ksub == 0) {
#pragma unroll
        for (int m = 0; m < GM; ++m) {
            atomicAdd(&y[(size_t)m * N + col0], acc0[m]);
            atomicAdd(&y[(size_t)m * N + col1], acc1[m]);
        }
    }
}

// ---------------- standalone GEMM for the output projection ----------------
__global__ __launch_bounds__(256) void gemm_v2(const float* __restrict__ x, int ldx,
                                               const float* __restrict__ w, int N,
                                               float* __restrict__ y) {
    __shared__ float xs[128][36];
    const int tid = threadIdx.x;
    const int k0 = blockIdx.y * 128;

    for (int j = tid; j < 32 * 32; j += 256) {
        const int m = j >> 5;
        const int kk = (j & 31) * 4;
        const float4 xv = *(const float4*)&x[(size_t)m * ldx + k0 + kk];
        xs[kk + 0][m] = xv.x; xs[kk + 1][m] = xv.y;
        xs[kk + 2][m] = xv.z; xs[kk + 3][m] = xv.w;
    }
    __syncthreads();

    const int ksub = tid & 3, cid = tid >> 2;
    const int col0 = blockIdx.x * 128 + cid;
    const int col1 = col0 + 64;
    float acc0[GM], acc1[GM];
#pragma unroll
    for (int m = 0; m < GM; ++m) { acc0[m] = 0.f; acc1[m] = 0.f; }

    for (int ii = 0; ii < 32; ++ii) {
        const int kl = ksub * 32 + ii;
        const float w0 = w[(size_t)(k0 + kl) * N + col0];
        const float w1 = w[(size_t)(k0 + kl) * N + col1];
#pragma unroll
        for (int m4 = 0; m4 < GM; m4 += 4) {
            const float4 xv = *(const float4*)&xs[kl][m4];
            acc0[m4 + 0] += xv.x * w0; acc1[m4 + 0] += xv.x * w1;
            acc0[m4 + 1] += xv.y * w0; acc1[m4 + 1] += xv.y * w1;
            acc0[m4 + 2] += xv.z * w0; acc1[m4 + 2] += xv.z * w1;
            acc0[m4 + 3] += xv.w * w0; acc1[m4 + 3] += xv.w * w1;
        }
    }
#pragma unroll
    for (int m = 0; m < GM; ++m) {
        acc0[m] += __shfl_xor(acc0[m], 1); acc0[m] += __shfl_xor(acc0[m], 2);
        acc1[m] += __shfl_xor(acc1[m], 1); acc1[m] += __shfl_xor(acc1[m], 2);
    }
    if (ksub == 0) {
#pragma unroll
        for (int m = 0; m < GM; ++m) {
            atomicAdd(&y[(size_t)m * N + col0], acc0[m]);
            atomicAdd(&y[(size_t)m * N + col1], acc1[m]);
        }
    }
}

// ---------------- rmsnorm + rope (unchanged) ----------------
__global__ __launch_bounds__(256) void qkv_post(const float* __restrict__ q_raw,
                                                const float* __restrict__ k_raw,
                                                const float* __restrict__ v_raw,
                                                const float* __restrict__ cosb,
                                                const float* __restrict__ sinb,
                                                const float* __restrict__ qnw,
                                                const float* __restrict__ knw,
                                                float* __restrict__ q_fin,
                                                float* __restrict__ kfull,
                                                float* __restrict__ vfull) {
    const int wid = (blockIdx.x * 256 + threadIdx.x) >> 6;
    const int lane = threadIdx.x & 63;
    if (wid < 1024) {
        const int m = wid >> 5, h = wid & 31;
        float v = q_raw[(size_t)m * 2048 + h * 64 + lane];
        float ss = v * v;
#pragma unroll
        for (int off = 32; off; off >>= 1) ss += __shfl_xor(ss, off);
        float nv = qnw[lane] * v * rsqrtf(ss * (1.f / 64.f) + EPS);
        float other = __shfl_xor(nv, 32);
        float rot = (lane < 32) ? -other : other;
        float outv = nv * cosb[m * 64 + lane] + rot * sinb[m * 64 + lane];
        q_fin[(size_t)m * 2048 + h * 64 + lane] = outv * SCALE;
    } else if (wid < 1280) {
        const int idx = wid - 1024;
        const int m = idx >> 3, g = idx & 7;
        float v = k_raw[(size_t)m * 512 + g * 64 + lane];
        float ss = v * v;
#pragma unroll
        for (int off = 32; off; off >>= 1) ss += __shfl_xor(ss, off);
        float nv = knw[lane] * v * rsqrtf(ss * (1.f / 64.f) + EPS);
        float other = __shfl_xor(nv, 32);
        float rot = (lane < 32) ? -other : other;
        float outv = nv * cosb[m * 64 + lane] + rot * sinb[m * 64 + lane];
        const int b = m >> 2, t = m & 3;
        kfull[((size_t)(b * HKV + g) * ST + S + t) * D + lane] = outv;
    } else if (wid < 1536) {
        const int idx = wid - 1280;
        const int m = idx >> 3, g = idx & 7;
        float v = v_raw[(size_t)m * 512 + g * 64 + lane];
        const int b = m >> 2, t = m & 3;
        vfull[((size_t)(b * HKV + g) * ST + S + t) * D + lane] = v;
    }
}

// ---------------- fused cache-copy + attention partials v5 ----------------
// Streaming decoupled from fragment access: coalesced float4 copy (HBM at copy
// efficiency), then MFMA frag reads re-read the 64KB chunk from hot L2.
// MFMA 16x16x32 maps: A: m=lane&15, k=(lane>>4)*8+e ; B: n=lane&15, same k
//                     C/D: col(n)=lane&15, row(m)=(lane>>4)*4+reg
__global__ __launch_bounds__(256) void attn_part(const float* __restrict__ q_fin,
                                                 const float* __restrict__ ck,
                                                 const float* __restrict__ cv,
                                                 float* __restrict__ kfull,
                                                 float* __restrict__ vfull,
                                                 float* __restrict__ o_part,
                                                 float* __restrict__ ml_part) {
    const int bg = blockIdx.x;            // 0..63
    const int c  = blockIdx.y;            // 0..NC-1
    const int b = bg >> 3, g = bg & 7;
    const int tid = threadIdx.x;
    const int lane = tid & 63;
    const int w = tid >> 6;               // wave 0..3
    const int q16 = lane & 15;
    const int kgrp = lane >> 4;           // 0..3

    __shared__ __align__(16) float sc[16][SCP];
    __shared__ __align__(16) _Float16 pb[16][PBP];
    __shared__ float mrow[16], lrow[16];

    const bool from_cache = (c < S / SC);
    const int valid = from_cache ? SC : (ST - S);   // 128 or 4
    const int vm1 = valid - 1;

    // ---- phase 0: coalesced streaming copy (the only HBM-heavy part) ----
    if (from_cache) {
        const float4* ksrc = (const float4*)(ck + ((size_t)bg * S + (size_t)c * SC) * D);
        const float4* vsrc = (const float4*)(cv + ((size_t)bg * S + (size_t)c * SC) * D);
        float4* kdst = (float4*)(kfull + ((size_t)bg * ST + (size_t)c * SC) * D);
        float4* vdst = (float4*)(vfull + ((size_t)bg * ST + (size_t)c * SC) * D);
#pragma unroll
        for (int i = 0; i < 8; ++i) {
            const float4 a = ksrc[tid + i * 256];
            const float4 bb = vsrc[tid + i * 256];
            kdst[tid + i * 256] = a;
            vdst[tid + i * 256] = bb;
        }
    }

    // ---- Q fragments (B-operand for QK^T): row q16, d = kgrp*8 + 32h ----
    half8 qf[2];
    {
        const float* qp = q_fin + ((size_t)(b * T + (q16 & 3)) * H + g * NREP + (q16 >> 2)) * D;
#pragma unroll
        for (int h = 0; h < 2; ++h) {
            const float* p = qp + h * 32 + kgrp * 8;
            qf[h] = cvt8(*(const float4*)p, *(const float4*)(p + 4));
        }
    }

    // ---- phase 1: QK^T via MFMA (frag reads hit L2) ----
    {
        const float* kb = from_cache ? (ck + ((size_t)bg * S + (size_t)c * SC) * D)
                                     : (kfull + ((size_t)bg * ST + (size_t)c * SC) * D);
#pragma unroll
        for (int t = 0; t < 2; ++t) {
            const int sl_raw = w * 32 + t * 16 + q16;          // A-frag row (chunk-local)
            const int sl = min(sl_raw, vm1);                   // clamp for tail
            const float* kp = kb + (size_t)sl * D + kgrp * 8;
            f32x4 acc = {0.f, 0.f, 0.f, 0.f};
#pragma unroll
            for (int h = 0; h < 2; ++h) {
                const float4 a = *(const float4*)(kp + h * 32);
                const float4 bb = *(const float4*)(kp + h * 32 + 4);
                acc = __builtin_amdgcn_mfma_f32_16x16x32_f16(cvt8(a, bb), qf[h], acc, 0, 0, 0);
            }
            const int sbase = w * 32 + t * 16 + kgrp * 4;
            if (sbase + 3 <= vm1) {
                *(f32x4*)&sc[q16][sbase] = acc;
            } else {
#pragma unroll
                for (int r = 0; r < 4; ++r)
                    sc[q16][sbase + r] = (sbase + r <= vm1) ? acc[r] : -1e30f;
            }
        }
    }
    __syncthreads();

    // ---- phase 2: per-row partial softmax; write P (f16) for PV ----
    for (int rr = 0; rr < 4; ++rr) {
        const int row = w * 4 + rr;
        const float v0 = sc[row][lane], v1 = sc[row][lane + 64];
        float m_ = fmaxf(v0, v1);
#pragma unroll
        for (int off = 32; off; off >>= 1) m_ = fmaxf(m_, __shfl_xor(m_, off));
        const float e0 = __expf(v0 - m_), e1 = __expf(v1 - m_);
        float l = e0 + e1;
#pragma unroll
        for (int off = 32; off; off >>= 1) l += __shfl_xor(l, off);
        pb[row][lane]      = (_Float16)e0;
        pb[row][lane + 64] = (_Float16)e1;
        if (lane == 0) { mrow[row] = m_; lrow[row] = l; }
    }
    __syncthreads();

    // ---- phase 3: PV via MFMA (V frag reads hit L2). wave w owns d-slice [16w,16w+16) ----
    {
        const float* vb = from_cache ? (cv + ((size_t)bg * S + (size_t)c * SC) * D)
                                     : (vfull + ((size_t)bg * ST + (size_t)c * SC) * D);
        const int dglob = w * 16 + q16;       // B-frag n-index (d)
        f32x4 oacc = {0.f, 0.f, 0.f, 0.f};
#pragma unroll
        for (int ks = 0; ks < 4; ++ks) {
            const int s0 = ks * 32;
            const half8 pa = *(const half8*)&pb[q16][s0 + kgrp * 8];
            half8 vf;
#pragma unroll
            for (int e = 0; e < 8; ++e) {
                const int sr = min(s0 + kgrp * 8 + e, vm1);
                vf[e] = (_Float16)vb[(size_t)sr * D + dglob];
            }
            oacc = __builtin_amdgcn_mfma_f32_16x16x32_f16(pa, vf, oacc, 0, 0, 0);
        }
#pragma unroll
        for (int r = 0; r < 4; ++r) {
            const int row = kgrp * 4 + r;     // q row (D m-index)
            o_part[(((size_t)bg * 16 + row) * NC + c) * 64 + dglob] = oacc[r];
        }
    }
    if (tid < 16) {
        ml_part[(((size_t)bg * 16 + tid) * NC + c) * 2 + 0] = mrow[tid];
        ml_part[(((size_t)bg * 16 + tid) * NC + c) * 2 + 1] = lrow[tid];
    }
}

// ---------------- combine partials (unchanged structure) ----------------
__global__ __launch_bounds__(256) void attn_combine(const float* __restrict__ o_part,
                                                    const float* __restrict__ ml_part,
                                                    float* __restrict__ og) {
    const int gw = (blockIdx.x * 256 + threadIdx.x) >> 6;  // 0..1023
    const int lane = threadIdx.x & 63;
    const int bg = gw >> 4, row = gw & 15;
    float M = -1e30f, L = 0.f, O = 0.f;
    for (int c = 0; c < NC; ++c) {
        const float m_ = ml_part[((size_t)gw * NC + c) * 2 + 0];
        const float l_ = ml_part[((size_t)gw * NC + c) * 2 + 1];
        const float o_ = o_part[((size_t)gw * NC + c) * 64 + lane];
        const float Mn = fmaxf(M, m_);
        const float fa = __expf(M - Mn), fb = __expf(m_ - Mn);
        O = O * fa + o_ * fb;
        L = L * fa + l_ * fb;
        M = Mn;
    }
    const float o = O / L;
    const int b = bg >> 3, g = bg & 7, r = row >> 2, t = row & 3;
    og[((size_t)(b * T + t) * H + (g * NREP + r)) * D + lane] = o;
}

extern "C" void kernel_launch(void* const* d_in, const int* in_sizes, int n_in,
                              void* d_out, int out_size, void* d_ws, size_t ws_size,
                              hipStream_t stream) {
    const float* x    = (const float*)d_in[0];
    const float* cosb = (const float*)d_in[1];
    const float* sinb = (const float*)d_in[2];
    const float* ck   = (const float*)d_in[3];
    const float* cv   = (const float*)d_in[4];
    const float* wq   = (const float*)d_in[5];
    const float* wk   = (const float*)d_in[6];
    const float* wvp  = (const float*)d_in[7];
    const float* wo   = (const float*)d_in[8];
    const float* qnw  = (const float*)d_in[9];
    const float* knw  = (const float*)d_in[10];

    float* out   = (float*)d_out;                       // [32][2048]
    float* kfull = out + 65536;                         // [B][HKV][ST][D]
    float* vfull = kfull + (size_t)B * HKV * ST * D;

    float* ws      = (float*)d_ws;
    float* q_raw   = ws;                    // 65536
    float* k_raw   = q_raw + 65536;         // 16384
    float* v_raw   = k_raw + 16384;         // 16384
    float* q_fin   = v_raw + 16384;         // 65536
    float* og      = q_fin + 65536;         // 65536
    float* o_part  = og + 65536;            // 64*16*NC*64
    float* ml_part = o_part + (size_t)64 * 16 * NC * 64;

    hipMemsetAsync(q_raw, 0, (size_t)(65536 + 16384 + 16384) * sizeof(float), stream);
    hipMemsetAsync(out, 0, (size_t)65536 * sizeof(float), stream);

    // fused q/k/v projections (one dispatch)
    gemm_qkv<<<dim3(24, 16), 256, 0, stream>>>(x, wq, wk, wvp, q_raw, k_raw, v_raw);

    qkv_post<<<384, 256, 0, stream>>>(q_raw, k_raw, v_raw, cosb, sinb, qnw, knw,
                                      q_fin, kfull, vfull);

    attn_part<<<dim3(64, NC), 256, 0, stream>>>(q_fin, ck, cv, kfull, vfull, o_part, ml_part);

    attn_combine<<<256, 256, 0, stream>>>(o_part, ml_part, og);

    gemm_v2<<<dim3(2048 / 128, 16), 256, 0, stream>>>(og, 2048, wo, 2048, out);
}